// Round 3
// baseline (374.071 us; speedup 1.0000x reference)
//
#include <hip/hip_runtime.h>

// deformMP: B=4, Cc=256, ci=64, H=W=128, GN groups=32, eps=1e-5
// ws layout (floats): xd[4.19M] offs[1.18M] osum[4.19M] t3[16.78M] mrs1[256] mrs2[256]
//                     w1T[16K] w3T[16K] wdT[36.9K] ps[2048]
// xdT (NHWC copy of xd, 4.19M) aliases t3[0..4.19M] (dead until conv2 rewrites it).

#define HW 16384
#define WIDTH 128

// ---- K0: transpose weights so inner-loop weight reads are wave-uniform (s_load) ----
__global__ __launch_bounds__(256) void k_prep(const float* __restrict__ w1, const float* __restrict__ w3,
                                              const float* __restrict__ wdef,
                                              float* __restrict__ w1T, float* __restrict__ w3T,
                                              float* __restrict__ wdT) {
  int i = blockIdx.x * 256 + threadIdx.x;
  if (i < 16384) { int o = i >> 8, c = i & 255; w1T[c * 64 + o] = w1[i]; }    // w1 [64][256] -> [c][o]
  if (i < 16384) { int o = i >> 6, c = i & 63;  w3T[c * 256 + o] = w3[i]; }   // w3 [256][64] -> [c][o]
  if (i < 36864) {                                                            // w_def [64][64][3][3] -> [k][c][o]
    int o = i / 576, r = i - o * 576;
    int c = r / 9, k = r - c * 9;
    wdT[(k * 64 + c) * 64 + o] = wdef[i];
  }
}

// ---- K1: conv1x1 256->64. Block=512 thr (8 waves): wave w -> 8 outputs, lane -> 1 float4 ----
__global__ __launch_bounds__(512) void k_conv1(const float* __restrict__ x, const float* __restrict__ w1T,
                                               float* __restrict__ y) {
  int tid = threadIdx.x;
  int lane = tid & 63;
  int o0 = __builtin_amdgcn_readfirstlane(tid >> 6) * 8;  // 8 waves x 8 outs = 64
  int b = blockIdx.x >> 6;
  int hw = ((blockIdx.x & 63) << 8) + (lane << 2);
  const float* xb = x + (size_t)b * 256 * HW + hw;
  float acc[8][4];
#pragma unroll
  for (int i = 0; i < 8; i++)
#pragma unroll
    for (int j = 0; j < 4; j++) acc[i][j] = 0.f;
  for (int c = 0; c < 256; c++) {
    float4 xv = *(const float4*)(xb + (size_t)c * HW);
    const float* wp = w1T + c * 64 + o0;  // wave-uniform -> s_load
#pragma unroll
    for (int i = 0; i < 8; i++) {
      float w = wp[i];
      acc[i][0] += xv.x * w; acc[i][1] += xv.y * w;
      acc[i][2] += xv.z * w; acc[i][3] += xv.w * w;
    }
  }
  float* yb = y + (size_t)b * 64 * HW + hw;
#pragma unroll
  for (int i = 0; i < 8; i++)
    *(float4*)(yb + (size_t)(o0 + i) * HW) = make_float4(acc[i][0], acc[i][1], acc[i][2], acc[i][3]);
}

// ---- K2a: GN stats partials. grid (128, S) ----
template <int CPG, int S>
__global__ __launch_bounds__(256) void k_gnstats_part(const float* __restrict__ y, float* __restrict__ ps) {
  int bg = blockIdx.x, sl = blockIdx.y;
  const int N4 = CPG * HW / 4 / S;
  const float4* p = (const float4*)(y + (size_t)bg * CPG * HW) + (size_t)sl * N4;
  float s = 0.f, ss = 0.f;
  for (int i = threadIdx.x; i < N4; i += 256) {
    float4 v = p[i];
    s += v.x + v.y + v.z + v.w;
    ss += v.x * v.x + v.y * v.y + v.z * v.z + v.w * v.w;
  }
#pragma unroll
  for (int off = 32; off; off >>= 1) { s += __shfl_down(s, off); ss += __shfl_down(ss, off); }
  __shared__ float ls[4], lss[4];
  int wv = threadIdx.x >> 6;
  if ((threadIdx.x & 63) == 0) { ls[wv] = s; lss[wv] = ss; }
  __syncthreads();
  if (threadIdx.x == 0) {
    ps[(bg * S + sl) * 2] = ls[0] + ls[1] + ls[2] + ls[3];
    ps[(bg * S + sl) * 2 + 1] = lss[0] + lss[1] + lss[2] + lss[3];
  }
}

// ---- K2b: finalize stats. 1 block, 128 threads (one per bg) ----
__global__ __launch_bounds__(128) void k_gnfin(const float* __restrict__ ps, float* __restrict__ mrs,
                                               int S, float n) {
  int bg = threadIdx.x;
  float s = 0.f, ss = 0.f;
  for (int sl = 0; sl < S; sl++) { s += ps[(bg * S + sl) * 2]; ss += ps[(bg * S + sl) * 2 + 1]; }
  float mu = s / n;
  float var = ss / n - mu * mu;
  mrs[bg] = mu;
  mrs[128 + bg] = rsqrtf(var + 1e-5f);
}

// ---- K3: apply GN1 + ReLU; write NCHW back in place AND NHWC copy via LDS transpose ----
__global__ __launch_bounds__(256) void k_gnapply_t(float* __restrict__ xd, float* __restrict__ xdT,
                                                   const float* __restrict__ mrs,
                                                   const float* __restrict__ g1, const float* __restrict__ b1) {
  __shared__ float tile[64 * 65];
  int tid = threadIdx.x;
  int b = blockIdx.x >> 8;            // 256 pixel-groups per batch
  int p0 = (blockIdx.x & 255) << 6;   // 64 pixels per block
  int lane = tid & 63;
  int w = tid >> 6;                   // 0..3
  const size_t bbase = (size_t)b * 64 * HW;
#pragma unroll
  for (int j = 0; j < 16; j++) {
    int c = w * 16 + j;
    int g = c >> 1;
    float mu = mrs[b * 32 + g], rs = mrs[128 + b * 32 + g];
    float ga = g1[c] * rs, be = b1[c] - mu * ga;
    float v = xd[bbase + (size_t)c * HW + p0 + lane];
    v = fmaxf(v * ga + be, 0.f);
    xd[bbase + (size_t)c * HW + p0 + lane] = v;   // NCHW (for k_off)
    tile[lane * 65 + c] = v;
  }
  __syncthreads();
#pragma unroll
  for (int j = 0; j < 16; j++) {
    int px = w * 16 + j;
    xdT[((size_t)b * HW + p0 + px) * 64 + lane] = tile[px * 65 + lane];  // NHWC (for deform)
  }
}

// ---- K4: conv3x3 64->18 (offsets), pad 1. grid (256, 2): 9 outs per block ----
__global__ __launch_bounds__(256) void k_off(const float* __restrict__ xd, const float* __restrict__ woff,
                                             float* __restrict__ offs) {
  int tid = threadIdx.x;
  int b = blockIdx.x >> 6;
  int r0 = (blockIdx.x & 63) << 1;
  int o0 = blockIdx.y * 9;
  int y = r0 + (tid >> 7);
  int xc = tid & 127;
  const float* xb = xd + (size_t)b * 64 * HW;
  float acc[9];
#pragma unroll
  for (int o = 0; o < 9; o++) acc[o] = 0.f;
  for (int c = 0; c < 64; c++) {
    const float* pc = xb + (size_t)c * HW;
    float v[3][3];
#pragma unroll
    for (int ky = 0; ky < 3; ky++) {
      int yy = y + ky - 1;
      bool vy = (unsigned)yy < 128u;
#pragma unroll
      for (int kx = 0; kx < 3; kx++) {
        int xx = xc + kx - 1;
        bool vx = (unsigned)xx < 128u;
        v[ky][kx] = (vy && vx) ? pc[yy * WIDTH + xx] : 0.f;
      }
    }
    const float* wc = woff + (size_t)(o0 * 64 + c) * 9;
#pragma unroll
    for (int o = 0; o < 9; o++) {
      const float* wo = wc + o * 576;  // uniform -> s_load
#pragma unroll
      for (int k = 0; k < 9; k++) acc[o] += v[k / 3][k % 3] * wo[k];
    }
  }
  float* op = offs + (size_t)b * 18 * HW + (size_t)o0 * HW + y * WIDTH + xc;
#pragma unroll
  for (int o = 0; o < 9; o++) op[(size_t)o * HW] = acc[o];
}

// ---- K5: deform conv v1 + residual, NHWC gathers, output split 2-way over blockIdx.y ----
__global__ __launch_bounds__(256) void k_deform2(const float* __restrict__ xt, const float* __restrict__ offs,
                                                 const float* __restrict__ wdT, float* __restrict__ osum) {
  int tid = threadIdx.x;
  int b = blockIdx.x >> 6;
  int pix = ((blockIdx.x & 63) << 8) + tid;
  int o0 = blockIdx.y << 5;  // 0 or 32
  int y = pix >> 7, xc = pix & 127;
  const float* ob = offs + (size_t)b * 18 * HW + pix;
  const float* xb = xt + (size_t)b * (64 * HW);  // [pix][64]
  float acc[32];
#pragma unroll
  for (int o = 0; o < 32; o++) acc[o] = 0.f;
#pragma unroll 1
  for (int k = 0; k < 9; k++) {
    float dy = ob[(size_t)(2 * k) * HW];
    float dx = ob[(size_t)(2 * k + 1) * HW];
    float py = (float)(y + k / 3 - 1) + dy;
    float px = (float)(xc + k % 3 - 1) + dx;
    float y0f = floorf(py), x0f = floorf(px);
    float ay = py - y0f, ax = px - x0f;
    int y0 = (int)y0f, x0 = (int)x0f;
    int y1i = y0 + 1, x1i = x0 + 1;
    float by0 = 1.f - ay, bx0 = 1.f - ax;
    bool vy0 = (unsigned)y0 < 128u, vy1 = (unsigned)y1i < 128u;
    bool vx0 = (unsigned)x0 < 128u, vx1 = (unsigned)x1i < 128u;
    float w00 = (vy0 && vx0) ? by0 * bx0 : 0.f;
    float w01 = (vy0 && vx1) ? by0 * ax : 0.f;
    float w10 = (vy1 && vx0) ? ay * bx0 : 0.f;
    float w11 = (vy1 && vx1) ? ay * ax : 0.f;
    int iy0 = min(max(y0, 0), 127), iy1 = min(max(y1i, 0), 127);
    int ix0 = min(max(x0, 0), 127), ix1 = min(max(x1i, 0), 127);
    int a00 = iy0 * WIDTH + ix0, a01 = iy0 * WIDTH + ix1;
    int a10 = iy1 * WIDTH + ix0, a11 = iy1 * WIDTH + ix1;
    const float* wk = wdT + (size_t)(k * 64) * 64 + o0;  // [c][64] slab for tap k
#pragma unroll 2
    for (int cc = 0; cc < 64; cc += 4) {
      float4 r00 = *(const float4*)(xb + (size_t)a00 * 64 + cc);
      float4 r01 = *(const float4*)(xb + (size_t)a01 * 64 + cc);
      float4 r10 = *(const float4*)(xb + (size_t)a10 * 64 + cc);
      float4 r11 = *(const float4*)(xb + (size_t)a11 * 64 + cc);
      float4 s;
      s.x = w00 * r00.x + w01 * r01.x + w10 * r10.x + w11 * r11.x;
      s.y = w00 * r00.y + w01 * r01.y + w10 * r10.y + w11 * r11.y;
      s.z = w00 * r00.z + w01 * r01.z + w10 * r10.z + w11 * r11.z;
      s.w = w00 * r00.w + w01 * r01.w + w10 * r10.w + w11 * r11.w;
      const float* wp = wk + cc * 64;  // uniform -> s_load
#pragma unroll
      for (int o = 0; o < 32; o++)
        acc[o] += s.x * wp[o] + s.y * wp[o + 64] + s.z * wp[o + 128] + s.w * wp[o + 192];
    }
  }
  const float* xr = xb + (size_t)pix * 64 + o0;  // residual (NHWC row)
  float* op = osum + (size_t)b * 64 * HW + pix;
#pragma unroll
  for (int o = 0; o < 32; o++) op[(size_t)(o0 + o) * HW] = acc[o] + xr[o];
}

// ---- K6: conv1x1 64->256 into t3; grid.y = 4 output-channel chunks of 64 ----
__global__ __launch_bounds__(256) void k_conv2(const float* __restrict__ osum, const float* __restrict__ w3T,
                                               float* __restrict__ t3) {
  int tid = threadIdx.x;
  int lane = tid & 63;
  int o0 = (blockIdx.y << 6) + __builtin_amdgcn_readfirstlane(tid >> 6) * 16;
  int b = blockIdx.x >> 6;
  int hw = ((blockIdx.x & 63) << 8) + (lane << 2);
  const float* ib = osum + (size_t)b * 64 * HW + hw;
  float acc[16][4];
#pragma unroll
  for (int i = 0; i < 16; i++)
#pragma unroll
    for (int j = 0; j < 4; j++) acc[i][j] = 0.f;
  for (int c = 0; c < 64; c++) {
    float4 xv = *(const float4*)(ib + (size_t)c * HW);
    const float* wp = w3T + c * 256 + o0;  // wave-uniform -> s_load
#pragma unroll
    for (int i = 0; i < 16; i++) {
      float w = wp[i];
      acc[i][0] += xv.x * w; acc[i][1] += xv.y * w;
      acc[i][2] += xv.z * w; acc[i][3] += xv.w * w;
    }
  }
  float* tb = t3 + (size_t)b * 256 * HW + hw;
#pragma unroll
  for (int i = 0; i < 16; i++)
    *(float4*)(tb + (size_t)(o0 + i) * HW) = make_float4(acc[i][0], acc[i][1], acc[i][2], acc[i][3]);
}

// ---- K8: out = relu(gn2(t3)) + x ----
__global__ __launch_bounds__(256) void k_final(const float* __restrict__ t3, const float* __restrict__ x,
                                               const float* __restrict__ mrs, const float* __restrict__ g3,
                                               const float* __restrict__ b3, float* __restrict__ out) {
  int i4 = blockIdx.x * 256 + threadIdx.x;
  int b = i4 >> 20;
  int c = (i4 >> 12) & 255;
  int g = c >> 3;
  float mu = mrs[b * 32 + g], rs = mrs[128 + b * 32 + g];
  float ga = g3[c] * rs, be = b3[c] - mu * ga;
  float4 t = ((const float4*)t3)[i4];
  float4 xv = ((const float4*)x)[i4];
  float4 r;
  r.x = fmaxf(t.x * ga + be, 0.f) + xv.x;
  r.y = fmaxf(t.y * ga + be, 0.f) + xv.y;
  r.z = fmaxf(t.z * ga + be, 0.f) + xv.z;
  r.w = fmaxf(t.w * ga + be, 0.f) + xv.w;
  ((float4*)out)[i4] = r;
}

extern "C" void kernel_launch(void* const* d_in, const int* in_sizes, int n_in,
                              void* d_out, int out_size, void* d_ws, size_t ws_size,
                              hipStream_t stream) {
  const float* x    = (const float*)d_in[0];
  const float* w1   = (const float*)d_in[1];
  const float* g1   = (const float*)d_in[2];
  const float* b1   = (const float*)d_in[3];
  const float* woff = (const float*)d_in[4];
  const float* wdef = (const float*)d_in[5];
  const float* w3   = (const float*)d_in[6];
  const float* g3   = (const float*)d_in[7];
  const float* b3   = (const float*)d_in[8];
  float* ws = (float*)d_ws;

  float* xd   = ws;                 // 4,194,304
  float* offs = xd + 4194304;       // 1,179,648
  float* osum = offs + 1179648;     // 4,194,304
  float* t3   = osum + 4194304;     // 16,777,216 (first 4.19M doubles as xdT)
  float* xdT  = t3;                 // alias: dead until conv2 rewrites t3
  float* mrs1 = t3 + 16777216;      // 256
  float* mrs2 = mrs1 + 256;         // 256
  float* w1T  = mrs2 + 256;         // 16,384
  float* w3T  = w1T + 16384;        // 16,384
  float* wdT  = w3T + 16384;        // 36,864
  float* ps   = wdT + 36864;        // 2,048
  float* out  = (float*)d_out;

  hipLaunchKernelGGL(k_prep, dim3(144), dim3(256), 0, stream, w1, w3, wdef, w1T, w3T, wdT);
  hipLaunchKernelGGL(k_conv1, dim3(256), dim3(512), 0, stream, x, w1T, xd);
  hipLaunchKernelGGL((k_gnstats_part<2, 4>), dim3(128, 4), dim3(256), 0, stream, xd, ps);
  hipLaunchKernelGGL(k_gnfin, dim3(1), dim3(128), 0, stream, ps, mrs1, 4, (float)(2 * HW));
  hipLaunchKernelGGL(k_gnapply_t, dim3(1024), dim3(256), 0, stream, xd, xdT, mrs1, g1, b1);
  hipLaunchKernelGGL(k_off, dim3(256, 2), dim3(256), 0, stream, xd, woff, offs);
  hipLaunchKernelGGL(k_deform2, dim3(256, 2), dim3(256), 0, stream, xdT, offs, wdT, osum);
  hipLaunchKernelGGL(k_conv2, dim3(256, 4), dim3(256), 0, stream, osum, w3T, t3);
  hipLaunchKernelGGL((k_gnstats_part<8, 8>), dim3(128, 8), dim3(256), 0, stream, t3, ps);
  hipLaunchKernelGGL(k_gnfin, dim3(1), dim3(128), 0, stream, ps, mrs2, 8, (float)(8 * HW));
  hipLaunchKernelGGL(k_final, dim3(16384), dim3(256), 0, stream, t3, x, mrs2, g3, b3, out);
}

// Round 4
// 315.658 us; speedup vs baseline: 1.1851x; 1.1851x over previous
//
#include <hip/hip_runtime.h>

// deformMP: B=4, Cc=256, ci=64, H=W=128, GN groups=32, eps=1e-5
// ws (floats): xd[4.19M] offs[1.18M] osum[4.19M] t3[16.78M] mrs1[256] mrs2[256]
//              w1T[16K] w3T[16K] wdT2[36.9K] ps[2048]   = 105.67 MB (proven budget)
// aliases: deform partials p0..p2 = t3[0..12.58M] (dead until conv2b rewrites t3)
//          wofT = t3[0..10752]   (consumed by k_off2 before deform writes partials)
//          ps2  = offs[0..65536] (offs dead after deform)

#define HW 16384
#define WIDTH 128

// ---- K0: weight repack ----
__global__ __launch_bounds__(256) void k_prep(const float* __restrict__ w1, const float* __restrict__ w3,
                                              const float* __restrict__ wdef, const float* __restrict__ woff,
                                              float* __restrict__ w1T, float* __restrict__ w3T,
                                              float* __restrict__ wdT2, float* __restrict__ wofT) {
  int i = blockIdx.x * 256 + threadIdx.x;
  if (i < 16384) { int o = i >> 8, c = i & 255; w1T[c * 64 + o] = w1[i]; }    // w1 [64][256] -> [c][o]
  if (i < 16384) { int o = i >> 6, c = i & 63;  w3T[c * 256 + o] = w3[i]; }   // w3 [256][64] -> [c][o]
  if (i < 36864) {                                                            // wdef [o][c][ky][kx] -> [kg][c][j][o]
    int o = i & 63;
    int t = i >> 6;        // (kg*64+c)*3 + j
    int j = t % 3;
    int t2 = t / 3;        // kg*64 + c
    int c = t2 & 63;
    int kg = t2 >> 6;
    wdT2[i] = wdef[((size_t)(o * 64 + c) * 3 + kg) * 3 + j];
  }
  if (i < 10752) {                                                            // woff [o][c][3][3] -> [g][c][o*9+k] pad 84
    int g = i / 5376;      // 64*84
    int r = i - g * 5376;
    int c = r / 84;
    int p = r - c * 84;
    float v = 0.f;
    if (p < 81) {
      int o = p / 9, k = p - o * 9;
      v = woff[((size_t)((g * 9 + o) * 64 + c)) * 9 + k];
    }
    wofT[i] = v;
  }
}

// ---- K1: conv1x1 256->64. Block=512 thr (8 waves): wave w -> 8 outputs, lane -> 1 float4 ----
__global__ __launch_bounds__(512) void k_conv1(const float* __restrict__ x, const float* __restrict__ w1T,
                                               float* __restrict__ y) {
  int tid = threadIdx.x;
  int lane = tid & 63;
  int o0 = __builtin_amdgcn_readfirstlane(tid >> 6) * 8;
  int b = blockIdx.x >> 6;
  int hw = ((blockIdx.x & 63) << 8) + (lane << 2);
  const float* xb = x + (size_t)b * 256 * HW + hw;
  float acc[8][4];
#pragma unroll
  for (int i = 0; i < 8; i++)
#pragma unroll
    for (int j = 0; j < 4; j++) acc[i][j] = 0.f;
#pragma unroll 4
  for (int c = 0; c < 256; c++) {
    float4 xv = *(const float4*)(xb + (size_t)c * HW);
    const float* wp = w1T + c * 64 + o0;  // wave-uniform -> s_load
#pragma unroll
    for (int i = 0; i < 8; i++) {
      float w = wp[i];
      acc[i][0] += xv.x * w; acc[i][1] += xv.y * w;
      acc[i][2] += xv.z * w; acc[i][3] += xv.w * w;
    }
  }
  float* yb = y + (size_t)b * 64 * HW + hw;
#pragma unroll
  for (int i = 0; i < 8; i++)
    *(float4*)(yb + (size_t)(o0 + i) * HW) = make_float4(acc[i][0], acc[i][1], acc[i][2], acc[i][3]);
}

// ---- K2a: GN1 stats partials. grid (128, S) ----
template <int CPG, int S>
__global__ __launch_bounds__(256) void k_gnstats_part(const float* __restrict__ y, float* __restrict__ ps) {
  int bg = blockIdx.x, sl = blockIdx.y;
  const int N4 = CPG * HW / 4 / S;
  const float4* p = (const float4*)(y + (size_t)bg * CPG * HW) + (size_t)sl * N4;
  float s = 0.f, ss = 0.f;
  for (int i = threadIdx.x; i < N4; i += 256) {
    float4 v = p[i];
    s += v.x + v.y + v.z + v.w;
    ss += v.x * v.x + v.y * v.y + v.z * v.z + v.w * v.w;
  }
#pragma unroll
  for (int off = 32; off; off >>= 1) { s += __shfl_down(s, off); ss += __shfl_down(ss, off); }
  __shared__ float ls[4], lss[4];
  int wv = threadIdx.x >> 6;
  if ((threadIdx.x & 63) == 0) { ls[wv] = s; lss[wv] = ss; }
  __syncthreads();
  if (threadIdx.x == 0) {
    ps[(bg * S + sl) * 2] = ls[0] + ls[1] + ls[2] + ls[3];
    ps[(bg * S + sl) * 2 + 1] = lss[0] + lss[1] + lss[2] + lss[3];
  }
}

// ---- K2b: finalize GN1 stats ----
__global__ __launch_bounds__(128) void k_gnfin(const float* __restrict__ ps, float* __restrict__ mrs,
                                               int S, float n) {
  int bg = threadIdx.x;
  float s = 0.f, ss = 0.f;
  for (int sl = 0; sl < S; sl++) { s += ps[(bg * S + sl) * 2]; ss += ps[(bg * S + sl) * 2 + 1]; }
  float mu = s / n;
  float var = ss / n - mu * mu;
  mrs[bg] = mu;
  mrs[128 + bg] = rsqrtf(var + 1e-5f);
}

// ---- K3: apply GN1 + ReLU in place on xd (NCHW) ----
__global__ __launch_bounds__(256) void k_gnapply1(float* __restrict__ xd, const float* __restrict__ mrs,
                                                  const float* __restrict__ g1, const float* __restrict__ b1) {
  int i4 = blockIdx.x * 256 + threadIdx.x;
  int b = i4 >> 18;
  int c = (i4 >> 12) & 63;
  int g = c >> 1;
  float mu = mrs[b * 32 + g], rs = mrs[128 + b * 32 + g];
  float ga = g1[c] * rs, be = b1[c] - mu * ga;
  float4 v = ((const float4*)xd)[i4];
  v.x = fmaxf(v.x * ga + be, 0.f);
  v.y = fmaxf(v.y * ga + be, 0.f);
  v.z = fmaxf(v.z * ga + be, 0.f);
  v.w = fmaxf(v.w * ga + be, 0.f);
  ((float4*)xd)[i4] = v;
}

// ---- K4: conv3x3 64->18 (offsets). grid (256, 2); weights staged in LDS ----
__global__ __launch_bounds__(256) void k_off2(const float* __restrict__ xd, const float* __restrict__ wofT,
                                              float* __restrict__ offs) {
  __shared__ float wl[64 * 84];  // 21.5 KB: [c][o*9+k] padded to 84
  int tid = threadIdx.x;
  int g = blockIdx.y;
  {
    const float4* src = (const float4*)(wofT + (size_t)g * 5376);
    float4* dst = (float4*)wl;
    for (int i = tid; i < 1344; i += 256) dst[i] = src[i];
  }
  __syncthreads();
  int b = blockIdx.x >> 6;
  int r0 = (blockIdx.x & 63) << 1;
  int y = r0 + (tid >> 7);
  int xc = tid & 127;
  const float* xb = xd + (size_t)b * 64 * HW;
  float acc[9];
#pragma unroll
  for (int o = 0; o < 9; o++) acc[o] = 0.f;
  for (int c = 0; c < 64; c++) {
    const float* pc = xb + (size_t)c * HW;
    float v[3][3];
#pragma unroll
    for (int ky = 0; ky < 3; ky++) {
      int yy = y + ky - 1;
      bool vy = (unsigned)yy < 128u;
#pragma unroll
      for (int kx = 0; kx < 3; kx++) {
        int xx = xc + kx - 1;
        bool vx = (unsigned)xx < 128u;
        v[ky][kx] = (vy && vx) ? pc[yy * WIDTH + xx] : 0.f;
      }
    }
    float wr[84];
    const float4* wc = (const float4*)(wl + c * 84);
#pragma unroll
    for (int q = 0; q < 21; q++) ((float4*)wr)[q] = wc[q];
#pragma unroll
    for (int o = 0; o < 9; o++)
#pragma unroll
      for (int k = 0; k < 9; k++) acc[o] += v[k / 3][k % 3] * wr[o * 9 + k];
  }
  float* op = offs + (size_t)b * 18 * HW + (size_t)(g * 9) * HW + y * WIDTH + xc;
#pragma unroll
  for (int o = 0; o < 9; o++) op[(size_t)o * HW] = acc[o];
}

// ---- K5: deform conv, NCHW gathers, 3-way tap split, LDS weights, pipelined gathers ----
__global__ __launch_bounds__(256) void k_deform5(const float* __restrict__ xd, const float* __restrict__ offs,
                                                 const float* __restrict__ wdT2, float* __restrict__ part) {
  __shared__ float wl[3 * 64 * 64];  // 48 KB: [c][j][o] for this kg
  int tid = threadIdx.x;
  int kg = blockIdx.y;
  {
    const float4* src = (const float4*)(wdT2 + (size_t)kg * 12288);
    float4* dst = (float4*)wl;
#pragma unroll
    for (int i = 0; i < 12; i++) dst[tid + i * 256] = src[tid + i * 256];
  }
  __syncthreads();
  int b = blockIdx.x >> 6;
  int pix = ((blockIdx.x & 63) << 8) + tid;
  int y = pix >> 7, xc = pix & 127;
  const float* ob = offs + (size_t)b * 18 * HW + pix;
  const float* xb = xd + (size_t)b * 64 * HW;
  float w00[3], w01[3], w10[3], w11[3];
  int a00[3], a01[3], a10[3], a11[3];
#pragma unroll
  for (int j = 0; j < 3; j++) {
    int k = kg * 3 + j;
    float dy = ob[(size_t)(2 * k) * HW];
    float dx = ob[(size_t)(2 * k + 1) * HW];
    float py = (float)(y + kg - 1) + dy;
    float px = (float)(xc + j - 1) + dx;
    float y0f = floorf(py), x0f = floorf(px);
    float ay = py - y0f, ax = px - x0f;
    int y0 = (int)y0f, x0 = (int)x0f;
    int y1i = y0 + 1, x1i = x0 + 1;
    float by0 = 1.f - ay, bx0 = 1.f - ax;
    bool vy0 = (unsigned)y0 < 128u, vy1 = (unsigned)y1i < 128u;
    bool vx0 = (unsigned)x0 < 128u, vx1 = (unsigned)x1i < 128u;
    w00[j] = (vy0 && vx0) ? by0 * bx0 : 0.f;
    w01[j] = (vy0 && vx1) ? by0 * ax : 0.f;
    w10[j] = (vy1 && vx0) ? ay * bx0 : 0.f;
    w11[j] = (vy1 && vx1) ? ay * ax : 0.f;
    int iy0 = min(max(y0, 0), 127), iy1 = min(max(y1i, 0), 127);
    int ix0 = min(max(x0, 0), 127), ix1 = min(max(x1i, 0), 127);
    a00[j] = iy0 * WIDTH + ix0; a01[j] = iy0 * WIDTH + ix1;
    a10[j] = iy1 * WIDTH + ix0; a11[j] = iy1 * WIDTH + ix1;
  }
  float acc[64];
#pragma unroll
  for (int o = 0; o < 64; o++) acc[o] = 0.f;
  float cv[12];
#pragma unroll
  for (int j = 0; j < 3; j++) {
    cv[4 * j + 0] = xb[a00[j]]; cv[4 * j + 1] = xb[a01[j]];
    cv[4 * j + 2] = xb[a10[j]]; cv[4 * j + 3] = xb[a11[j]];
  }
#pragma unroll 1
  for (int c = 0; c < 64; c++) {
    float s0 = w00[0] * cv[0] + w01[0] * cv[1] + w10[0] * cv[2] + w11[0] * cv[3];
    float s1 = w00[1] * cv[4] + w01[1] * cv[5] + w10[1] * cv[6] + w11[1] * cv[7];
    float s2 = w00[2] * cv[8] + w01[2] * cv[9] + w10[2] * cv[10] + w11[2] * cv[11];
    float nv[12];
    if (c < 63) {
      const float* pn = xb + (size_t)(c + 1) * HW;
#pragma unroll
      for (int j = 0; j < 3; j++) {
        nv[4 * j + 0] = pn[a00[j]]; nv[4 * j + 1] = pn[a01[j]];
        nv[4 * j + 2] = pn[a10[j]]; nv[4 * j + 3] = pn[a11[j]];
      }
    }
    const float4* wc = (const float4*)(wl + c * 192);
#pragma unroll
    for (int q = 0; q < 16; q++) {
      float4 u0 = wc[q];
      float4 u1 = wc[q + 16];
      float4 u2 = wc[q + 32];
      acc[4 * q + 0] += s0 * u0.x + s1 * u1.x + s2 * u2.x;
      acc[4 * q + 1] += s0 * u0.y + s1 * u1.y + s2 * u2.y;
      acc[4 * q + 2] += s0 * u0.z + s1 * u1.z + s2 * u2.z;
      acc[4 * q + 3] += s0 * u0.w + s1 * u1.w + s2 * u2.w;
    }
    if (c < 63) {
#pragma unroll
      for (int t = 0; t < 12; t++) cv[t] = nv[t];
    }
  }
  float* op = part + (size_t)kg * 4194304 + (size_t)b * 64 * HW + pix;
#pragma unroll
  for (int o = 0; o < 64; o++) op[(size_t)o * HW] = acc[o];
}

// ---- K5b: osum = p0 + p1 + p2 + xd (residual) ----
__global__ __launch_bounds__(256) void k_dreduce(const float* __restrict__ part, const float* __restrict__ xd,
                                                 float* __restrict__ osum) {
  int i4 = blockIdx.x * 256 + threadIdx.x;
  const float4* p0 = (const float4*)part;
  const float4* p1 = (const float4*)(part + 4194304);
  const float4* p2 = (const float4*)(part + 8388608);
  const float4* xp = (const float4*)xd;
  float4 a = p0[i4], b = p1[i4], c = p2[i4], d = xp[i4];
  float4 r;
  r.x = a.x + b.x + c.x + d.x;
  r.y = a.y + b.y + c.y + d.y;
  r.z = a.z + b.z + c.z + d.z;
  r.w = a.w + b.w + c.w + d.w;
  ((float4*)osum)[i4] = r;
}

// ---- K6: conv1x1 64->256 + fused GN2 partial stats. Block = 64 px, all 256 outs ----
__global__ __launch_bounds__(256) void k_conv2b(const float* __restrict__ osum, const float* __restrict__ w3T,
                                                float* __restrict__ t3, float* __restrict__ ps2) {
  __shared__ float wl[64 * 256];  // 64 KB: [c][o]
  int tid = threadIdx.x;
  {
    const float4* src = (const float4*)w3T;
    float4* dst = (float4*)wl;
#pragma unroll
    for (int i = 0; i < 16; i++) dst[tid + i * 256] = src[tid + i * 256];
  }
  __syncthreads();
  int lane = tid & 63;
  int w = __builtin_amdgcn_readfirstlane(tid >> 6);  // wave 0..3 -> out chans w*64..
  int b = blockIdx.x >> 8;
  int chunk = blockIdx.x & 255;
  int px0 = chunk << 6;
  const float* ib = osum + (size_t)b * 64 * HW + px0 + lane;
  float acc[64];
#pragma unroll
  for (int o = 0; o < 64; o++) acc[o] = 0.f;
#pragma unroll 2
  for (int c = 0; c < 64; c++) {
    float v = ib[(size_t)c * HW];
    const float4* wc = (const float4*)(wl + c * 256 + w * 64);
#pragma unroll
    for (int q = 0; q < 16; q++) {
      float4 u = wc[q];
      acc[4 * q + 0] += v * u.x;
      acc[4 * q + 1] += v * u.y;
      acc[4 * q + 2] += v * u.z;
      acc[4 * q + 3] += v * u.w;
    }
  }
  float* tb = t3 + (size_t)b * 256 * HW + (size_t)(w * 64) * HW + px0 + lane;
#pragma unroll
  for (int o = 0; o < 64; o++) tb[(size_t)o * HW] = acc[o];
  // GN2 partial stats: wave's 64 chans = 8 groups of 8
  float s[8], ss[8];
#pragma unroll
  for (int g = 0; g < 8; g++) {
    float a = 0.f, q = 0.f;
#pragma unroll
    for (int i = 0; i < 8; i++) { float v = acc[g * 8 + i]; a += v; q += v * v; }
    s[g] = a; ss[g] = q;
  }
#pragma unroll
  for (int g = 0; g < 8; g++) {
#pragma unroll
    for (int off = 32; off; off >>= 1) { s[g] += __shfl_down(s[g], off); ss[g] += __shfl_down(ss[g], off); }
  }
  if (lane == 0) {
#pragma unroll
    for (int g = 0; g < 8; g++) {
      int bg = b * 32 + w * 8 + g;
      ps2[(bg * 256 + chunk) * 2] = s[g];
      ps2[(bg * 256 + chunk) * 2 + 1] = ss[g];
    }
  }
}

// ---- K7: finalize GN2 stats (256 chunks per bg) ----
__global__ __launch_bounds__(128) void k_gnfin2(const float* __restrict__ ps2, float* __restrict__ mrs) {
  int bg = threadIdx.x;
  float s = 0.f, ss = 0.f;
  for (int ch = 0; ch < 256; ch++) { s += ps2[(bg * 256 + ch) * 2]; ss += ps2[(bg * 256 + ch) * 2 + 1]; }
  const float n = 131072.f;  // 8 chans * 16384 px
  float mu = s / n;
  float var = ss / n - mu * mu;
  mrs[bg] = mu;
  mrs[128 + bg] = rsqrtf(var + 1e-5f);
}

// ---- K8: out = relu(gn2(t3)) + x ----
__global__ __launch_bounds__(256) void k_final(const float* __restrict__ t3, const float* __restrict__ x,
                                               const float* __restrict__ mrs, const float* __restrict__ g3,
                                               const float* __restrict__ b3, float* __restrict__ out) {
  int i4 = blockIdx.x * 256 + threadIdx.x;
  int b = i4 >> 20;
  int c = (i4 >> 12) & 255;
  int g = c >> 3;
  float mu = mrs[b * 32 + g], rs = mrs[128 + b * 32 + g];
  float ga = g3[c] * rs, be = b3[c] - mu * ga;
  float4 t = ((const float4*)t3)[i4];
  float4 xv = ((const float4*)x)[i4];
  float4 r;
  r.x = fmaxf(t.x * ga + be, 0.f) + xv.x;
  r.y = fmaxf(t.y * ga + be, 0.f) + xv.y;
  r.z = fmaxf(t.z * ga + be, 0.f) + xv.z;
  r.w = fmaxf(t.w * ga + be, 0.f) + xv.w;
  ((float4*)out)[i4] = r;
}

extern "C" void kernel_launch(void* const* d_in, const int* in_sizes, int n_in,
                              void* d_out, int out_size, void* d_ws, size_t ws_size,
                              hipStream_t stream) {
  const float* x    = (const float*)d_in[0];
  const float* w1   = (const float*)d_in[1];
  const float* g1   = (const float*)d_in[2];
  const float* b1   = (const float*)d_in[3];
  const float* woff = (const float*)d_in[4];
  const float* wdef = (const float*)d_in[5];
  const float* w3   = (const float*)d_in[6];
  const float* g3   = (const float*)d_in[7];
  const float* b3   = (const float*)d_in[8];
  float* ws = (float*)d_ws;

  float* xd   = ws;                 // 4,194,304
  float* offs = xd + 4194304;       // 1,179,648
  float* osum = offs + 1179648;     // 4,194,304
  float* t3   = osum + 4194304;     // 16,777,216
  float* mrs1 = t3 + 16777216;      // 256
  float* mrs2 = mrs1 + 256;         // 256
  float* w1T  = mrs2 + 256;         // 16,384
  float* w3T  = w1T + 16384;        // 16,384
  float* wdT2 = w3T + 16384;        // 36,864
  float* ps   = wdT2 + 36864;       // 2,048
  float* wofT = t3;                 // alias: consumed by k_off2 before partials written
  float* part = t3;                 // alias: deform partials, dead once conv2b rewrites t3
  float* ps2  = offs;               // alias: offs dead after deform
  float* out  = (float*)d_out;

  hipLaunchKernelGGL(k_prep, dim3(144), dim3(256), 0, stream, w1, w3, wdef, woff, w1T, w3T, wdT2, wofT);
  hipLaunchKernelGGL(k_conv1, dim3(256), dim3(512), 0, stream, x, w1T, xd);
  hipLaunchKernelGGL((k_gnstats_part<2, 4>), dim3(128, 4), dim3(256), 0, stream, xd, ps);
  hipLaunchKernelGGL(k_gnfin, dim3(1), dim3(128), 0, stream, ps, mrs1, 4, (float)(2 * HW));
  hipLaunchKernelGGL(k_gnapply1, dim3(4096), dim3(256), 0, stream, xd, mrs1, g1, b1);
  hipLaunchKernelGGL(k_off2, dim3(256, 2), dim3(256), 0, stream, xd, wofT, offs);
  hipLaunchKernelGGL(k_deform5, dim3(256, 3), dim3(256), 0, stream, xd, offs, wdT2, part);
  hipLaunchKernelGGL(k_dreduce, dim3(4096), dim3(256), 0, stream, part, xd, osum);
  hipLaunchKernelGGL(k_conv2b, dim3(1024), dim3(256), 0, stream, osum, w3T, t3, ps2);
  hipLaunchKernelGGL(k_gnfin2, dim3(1), dim3(128), 0, stream, ps2, mrs2);
  hipLaunchKernelGGL(k_final, dim3(16384), dim3(256), 0, stream, t3, x, mrs2, g3, b3, out);
}

// Round 6
// 288.323 us; speedup vs baseline: 1.2974x; 1.0948x over previous
//
#include <hip/hip_runtime.h>

// deformMP: B=4, Cc=256, ci=64, H=W=128, GN groups=32, eps=1e-5
// ws (floats): xd[4.19M] offs[1.18M] osum[4.19M] t3[16.78M] mrs1[256] mrs2[256]
//              w1T[16K] w3T[16K] (gap 36.9K) ps[2048]   (same 105.67 MB budget)
// aliases in t3 (dead until conv2b rewrites t3):
//   wofT = t3[0..10752)            (read by k_off2)
//   wBf  = (ushort*)(t3 + 16384), 36864 bf16  (read by k_deform_mfma)
//   ps2  = offs (offs dead after deform build phase)

#define HW 16384
#define WIDTH 128
#define APAD 584  // A-row stride in bf16 elems (1168 B = 73*16)

typedef __attribute__((ext_vector_type(8))) short bf16x8;
typedef __attribute__((ext_vector_type(4))) float f32x4;

__device__ __forceinline__ unsigned short f2bf(float f) {
  unsigned int u = __float_as_uint(f);
  u = (u + 0x7fffu + ((u >> 16) & 1u)) >> 16;  // RNE
  return (unsigned short)u;
}

// ---- K0: weight repack ----
__global__ __launch_bounds__(256) void k_prep(const float* __restrict__ w1, const float* __restrict__ w3,
                                              const float* __restrict__ wdef, const float* __restrict__ woff,
                                              float* __restrict__ w1T, float* __restrict__ w3T,
                                              unsigned short* __restrict__ wBf, float* __restrict__ wofT) {
  int i = blockIdx.x * 256 + threadIdx.x;
  if (i < 16384) { int o = i >> 8, c = i & 255; w1T[c * 64 + o] = w1[i]; }    // w1 [64][256] -> [c][o]
  if (i < 16384) { int o = i >> 6, c = i & 63;  w3T[c * 256 + o] = w3[i]; }   // w3 [256][64] -> [c][o]
  if (i < 36864) {
    // B-fragments for mfma 16x16x32: [kt=18][n=4][lane=64][j=8], elem = W[K=kt*32+(lane>>4)*8+j][o=n*16+(lane&15)]
    // K index = tap*64 + c ; wdef [o][c][3][3]
    int j = i & 7;
    int lane = (i >> 3) & 63;
    int n = (i >> 9) & 3;
    int kt = i >> 11;
    int kk = kt * 32 + ((lane >> 4) << 3) + j;
    int tap = kk >> 6, c = kk & 63;
    int o = (n << 4) + (lane & 15);
    wBf[i] = f2bf(wdef[(size_t)o * 576 + c * 9 + tap]);
  }
  if (i < 10752) {                                                            // woff [18][64][3][3] -> [g][c][o*9+k] pad 84
    int g = i / 5376;
    int r = i - g * 5376;
    int c = r / 84;
    int p = r - c * 84;
    float v = 0.f;
    if (p < 81) {
      int o = p / 9, k = p - o * 9;
      v = woff[((size_t)((g * 9 + o) * 64 + c)) * 9 + k];
    }
    wofT[i] = v;
  }
}

// ---- K1: conv1x1 256->64. Block=512 thr (8 waves): wave w -> 8 outputs, lane -> 1 float4 ----
__global__ __launch_bounds__(512) void k_conv1(const float* __restrict__ x, const float* __restrict__ w1T,
                                               float* __restrict__ y) {
  int tid = threadIdx.x;
  int lane = tid & 63;
  int o0 = __builtin_amdgcn_readfirstlane(tid >> 6) * 8;
  int b = blockIdx.x >> 6;
  int hw = ((blockIdx.x & 63) << 8) + (lane << 2);
  const float* xb = x + (size_t)b * 256 * HW + hw;
  float acc[8][4];
#pragma unroll
  for (int i = 0; i < 8; i++)
#pragma unroll
    for (int j = 0; j < 4; j++) acc[i][j] = 0.f;
#pragma unroll 4
  for (int c = 0; c < 256; c++) {
    float4 xv = *(const float4*)(xb + (size_t)c * HW);
    const float* wp = w1T + c * 64 + o0;  // wave-uniform -> s_load
#pragma unroll
    for (int i = 0; i < 8; i++) {
      float w = wp[i];
      acc[i][0] += xv.x * w; acc[i][1] += xv.y * w;
      acc[i][2] += xv.z * w; acc[i][3] += xv.w * w;
    }
  }
  float* yb = y + (size_t)b * 64 * HW + hw;
#pragma unroll
  for (int i = 0; i < 8; i++)
    *(float4*)(yb + (size_t)(o0 + i) * HW) = make_float4(acc[i][0], acc[i][1], acc[i][2], acc[i][3]);
}

// ---- K2a: GN1 stats partials. grid (128, S) ----
template <int CPG, int S>
__global__ __launch_bounds__(256) void k_gnstats_part(const float* __restrict__ y, float* __restrict__ ps) {
  int bg = blockIdx.x, sl = blockIdx.y;
  const int N4 = CPG * HW / 4 / S;
  const float4* p = (const float4*)(y + (size_t)bg * CPG * HW) + (size_t)sl * N4;
  float s = 0.f, ss = 0.f;
  for (int i = threadIdx.x; i < N4; i += 256) {
    float4 v = p[i];
    s += v.x + v.y + v.z + v.w;
    ss += v.x * v.x + v.y * v.y + v.z * v.z + v.w * v.w;
  }
#pragma unroll
  for (int off = 32; off; off >>= 1) { s += __shfl_down(s, off); ss += __shfl_down(ss, off); }
  __shared__ float ls[4], lss[4];
  int wv = threadIdx.x >> 6;
  if ((threadIdx.x & 63) == 0) { ls[wv] = s; lss[wv] = ss; }
  __syncthreads();
  if (threadIdx.x == 0) {
    ps[(bg * S + sl) * 2] = ls[0] + ls[1] + ls[2] + ls[3];
    ps[(bg * S + sl) * 2 + 1] = lss[0] + lss[1] + lss[2] + lss[3];
  }
}

// ---- K2b: finalize GN1 stats ----
__global__ __launch_bounds__(128) void k_gnfin(const float* __restrict__ ps, float* __restrict__ mrs,
                                               int S, float n) {
  int bg = threadIdx.x;
  float s = 0.f, ss = 0.f;
  for (int sl = 0; sl < S; sl++) { s += ps[(bg * S + sl) * 2]; ss += ps[(bg * S + sl) * 2 + 1]; }
  float mu = s / n;
  float var = ss / n - mu * mu;
  mrs[bg] = mu;
  mrs[128 + bg] = rsqrtf(var + 1e-5f);
}

// ---- K3: apply GN1 + ReLU in place on xd (NCHW) ----
__global__ __launch_bounds__(256) void k_gnapply1(float* __restrict__ xd, const float* __restrict__ mrs,
                                                  const float* __restrict__ g1, const float* __restrict__ b1) {
  int i4 = blockIdx.x * 256 + threadIdx.x;
  int b = i4 >> 18;
  int c = (i4 >> 12) & 63;
  int g = c >> 1;
  float mu = mrs[b * 32 + g], rs = mrs[128 + b * 32 + g];
  float ga = g1[c] * rs, be = b1[c] - mu * ga;
  float4 v = ((const float4*)xd)[i4];
  v.x = fmaxf(v.x * ga + be, 0.f);
  v.y = fmaxf(v.y * ga + be, 0.f);
  v.z = fmaxf(v.z * ga + be, 0.f);
  v.w = fmaxf(v.w * ga + be, 0.f);
  ((float4*)xd)[i4] = v;
}

// ---- K4: conv3x3 64->18 (offsets). grid (256, 2); weights staged in LDS ----
__global__ __launch_bounds__(256) void k_off2(const float* __restrict__ xd, const float* __restrict__ wofT,
                                              float* __restrict__ offs) {
  __shared__ float wl[64 * 84];
  int tid = threadIdx.x;
  int g = blockIdx.y;
  {
    const float4* src = (const float4*)(wofT + (size_t)g * 5376);
    float4* dst = (float4*)wl;
    for (int i = tid; i < 1344; i += 256) dst[i] = src[i];
  }
  __syncthreads();
  int b = blockIdx.x >> 6;
  int r0 = (blockIdx.x & 63) << 1;
  int y = r0 + (tid >> 7);
  int xc = tid & 127;
  const float* xb = xd + (size_t)b * 64 * HW;
  float acc[9];
#pragma unroll
  for (int o = 0; o < 9; o++) acc[o] = 0.f;
  for (int c = 0; c < 64; c++) {
    const float* pc = xb + (size_t)c * HW;
    float v[3][3];
#pragma unroll
    for (int ky = 0; ky < 3; ky++) {
      int yy = y + ky - 1;
      bool vy = (unsigned)yy < 128u;
#pragma unroll
      for (int kx = 0; kx < 3; kx++) {
        int xx = xc + kx - 1;
        bool vx = (unsigned)xx < 128u;
        v[ky][kx] = (vy && vx) ? pc[yy * WIDTH + xx] : 0.f;
      }
    }
    float wr[84];
    const float4* wc = (const float4*)(wl + c * 84);
#pragma unroll
    for (int q = 0; q < 21; q++) ((float4*)wr)[q] = wc[q];
#pragma unroll
    for (int o = 0; o < 9; o++)
#pragma unroll
      for (int k = 0; k < 9; k++) acc[o] += v[k / 3][k % 3] * wr[o * 9 + k];
  }
  float* op = offs + (size_t)b * 18 * HW + (size_t)(g * 9) * HW + y * WIDTH + xc;
#pragma unroll
  for (int o = 0; o < 9; o++) op[(size_t)o * HW] = acc[o];
}

// ---- K5: deform conv via bf16 MFMA. Block = 576 thr (9 waves), tile = 64 px, all taps/outs.
// Build: wave=tap, lane=px -> A[64px][576K] bf16 in LDS (K = tap*64+c).
// GEMM: waves 0..7 = (m-half, o-tile): D[64px][64o] = A @ W, + residual, -> osum (NCHW).
__global__ __launch_bounds__(576, 5) void k_deform_mfma(const float* __restrict__ xd,
                                                        const float* __restrict__ offs,
                                                        const unsigned short* __restrict__ wBf,
                                                        float* __restrict__ osum) {
  __shared__ unsigned short A[64 * APAD];  // 74,752 B
  int tid = threadIdx.x;
  int bb = blockIdx.x >> 8;
  int tile = blockIdx.x & 255;
  int px0 = tile << 6;
  const float* xb = xd + (size_t)bb * 64 * HW;

  // ---- build phase: one (px, tap) pair per thread ----
  {
    int tap = tid >> 6;   // 0..8
    int pxl = tid & 63;
    int px = px0 + pxl;
    int y = px >> 7, xc = px & 127;
    const float* ob = offs + (size_t)bb * 18 * HW + px0 + pxl;
    float dy = ob[(size_t)(2 * tap) * HW];
    float dx = ob[(size_t)(2 * tap + 1) * HW];
    float py = (float)(y + tap / 3 - 1) + dy;
    float pxx = (float)(xc + tap % 3 - 1) + dx;
    float y0f = floorf(py), x0f = floorf(pxx);
    float ay = py - y0f, ax = pxx - x0f;
    int y0 = (int)y0f, x0 = (int)x0f;
    int y1i = y0 + 1, x1i = x0 + 1;
    float by0 = 1.f - ay, bx0 = 1.f - ax;
    bool vy0 = (unsigned)y0 < 128u, vy1 = (unsigned)y1i < 128u;
    bool vx0 = (unsigned)x0 < 128u, vx1 = (unsigned)x1i < 128u;
    float w00 = (vy0 && vx0) ? by0 * bx0 : 0.f;
    float w01 = (vy0 && vx1) ? by0 * ax : 0.f;
    float w10 = (vy1 && vx0) ? ay * bx0 : 0.f;
    float w11 = (vy1 && vx1) ? ay * ax : 0.f;
    int iy0 = min(max(y0, 0), 127), iy1 = min(max(y1i, 0), 127);
    int ix0 = min(max(x0, 0), 127), ix1 = min(max(x1i, 0), 127);
    int a00 = iy0 * WIDTH + ix0, a01 = iy0 * WIDTH + ix1;
    int a10 = iy1 * WIDTH + ix0, a11 = iy1 * WIDTH + ix1;
    unsigned short* arow = &A[pxl * APAD + tap * 64];
#pragma unroll 1
    for (int c0 = 0; c0 < 64; c0 += 8) {
      unsigned int pk[4];
#pragma unroll
      for (int q = 0; q < 4; q++) {
        const float* p0 = xb + (size_t)(c0 + 2 * q) * HW;
        const float* p1 = p0 + HW;
        float v0 = w00 * p0[a00] + w01 * p0[a01] + w10 * p0[a10] + w11 * p0[a11];
        float v1 = w00 * p1[a00] + w01 * p1[a01] + w10 * p1[a10] + w11 * p1[a11];
        pk[q] = (unsigned int)f2bf(v0) | ((unsigned int)f2bf(v1) << 16);
      }
      *(uint4*)(arow + c0) = make_uint4(pk[0], pk[1], pk[2], pk[3]);
    }
  }
  __syncthreads();

  // ---- GEMM phase: waves 0..7 ----
  int wave = tid >> 6;
  if (wave >= 8) return;
  int lane = tid & 63;
  int n = wave & 3;        // o-tile (16 outs)
  int mh = wave >> 2;      // m-half (32 px)
  int r0 = mh * 32 + (lane & 15);
  int koff = ((lane >> 4) << 3);
  const bf16x8* wp = (const bf16x8*)wBf;
  f32x4 acc0 = {0.f, 0.f, 0.f, 0.f};
  f32x4 acc1 = {0.f, 0.f, 0.f, 0.f};
#pragma unroll 2
  for (int kt = 0; kt < 18; kt++) {
    bf16x8 bk = wp[(kt * 4 + n) * 64 + lane];  // L2-hot, per-lane contiguous 16B
    bf16x8 a0 = *(const bf16x8*)&A[r0 * APAD + kt * 32 + koff];
    bf16x8 a1 = *(const bf16x8*)&A[(r0 + 16) * APAD + kt * 32 + koff];
    acc0 = __builtin_amdgcn_mfma_f32_16x16x32_bf16(a0, bk, acc0, 0, 0, 0);
    acc1 = __builtin_amdgcn_mfma_f32_16x16x32_bf16(a1, bk, acc1, 0, 0, 0);
  }
  // epilogue: D col = lane&15 (o), row = (lane>>4)*4 + r (px); + residual
  int o = n * 16 + (lane & 15);
  int prow = mh * 32 + ((lane >> 4) << 2);
  float* op = osum + (size_t)bb * 64 * HW + (size_t)o * HW + px0 + prow;
  const float* xr = xb + (size_t)o * HW + px0 + prow;
#pragma unroll
  for (int r = 0; r < 4; r++) {
    op[r] = acc0[r] + xr[r];
    op[16 + r] = acc1[r] + xr[16 + r];
  }
}

// ---- K6: conv1x1 64->256 + fused GN2 partial stats. Block = 64 px, all 256 outs ----
__global__ __launch_bounds__(256) void k_conv2b(const float* __restrict__ osum, const float* __restrict__ w3T,
                                                float* __restrict__ t3, float* __restrict__ ps2) {
  __shared__ float wl[64 * 256];
  int tid = threadIdx.x;
  {
    const float4* src = (const float4*)w3T;
    float4* dst = (float4*)wl;
#pragma unroll
    for (int i = 0; i < 16; i++) dst[tid + i * 256] = src[tid + i * 256];
  }
  __syncthreads();
  int lane = tid & 63;
  int w = __builtin_amdgcn_readfirstlane(tid >> 6);
  int b = blockIdx.x >> 8;
  int chunk = blockIdx.x & 255;
  int px0 = chunk << 6;
  const float* ib = osum + (size_t)b * 64 * HW + px0 + lane;
  float acc[64];
#pragma unroll
  for (int o = 0; o < 64; o++) acc[o] = 0.f;
#pragma unroll 2
  for (int c = 0; c < 64; c++) {
    float v = ib[(size_t)c * HW];
    const float4* wc = (const float4*)(wl + c * 256 + w * 64);
#pragma unroll
    for (int q = 0; q < 16; q++) {
      float4 u = wc[q];
      acc[4 * q + 0] += v * u.x;
      acc[4 * q + 1] += v * u.y;
      acc[4 * q + 2] += v * u.z;
      acc[4 * q + 3] += v * u.w;
    }
  }
  float* tb = t3 + (size_t)b * 256 * HW + (size_t)(w * 64) * HW + px0 + lane;
#pragma unroll
  for (int o = 0; o < 64; o++) tb[(size_t)o * HW] = acc[o];
  float s[8], ss[8];
#pragma unroll
  for (int g = 0; g < 8; g++) {
    float a = 0.f, q = 0.f;
#pragma unroll
    for (int i = 0; i < 8; i++) { float v = acc[g * 8 + i]; a += v; q += v * v; }
    s[g] = a; ss[g] = q;
  }
#pragma unroll
  for (int g = 0; g < 8; g++) {
#pragma unroll
    for (int off = 32; off; off >>= 1) { s[g] += __shfl_down(s[g], off); ss[g] += __shfl_down(ss[g], off); }
  }
  if (lane == 0) {
#pragma unroll
    for (int g = 0; g < 8; g++) {
      int bg = b * 32 + w * 8 + g;
      ps2[(bg * 256 + chunk) * 2] = s[g];
      ps2[(bg * 256 + chunk) * 2 + 1] = ss[g];
    }
  }
}

// ---- K7: finalize GN2 stats ----
__global__ __launch_bounds__(128) void k_gnfin2(const float* __restrict__ ps2, float* __restrict__ mrs) {
  int bg = threadIdx.x;
  float s = 0.f, ss = 0.f;
  for (int ch = 0; ch < 256; ch++) { s += ps2[(bg * 256 + ch) * 2]; ss += ps2[(bg * 256 + ch) * 2 + 1]; }
  const float n = 131072.f;
  float mu = s / n;
  float var = ss / n - mu * mu;
  mrs[bg] = mu;
  mrs[128 + bg] = rsqrtf(var + 1e-5f);
}

// ---- K8: out = relu(gn2(t3)) + x ----
__global__ __launch_bounds__(256) void k_final(const float* __restrict__ t3, const float* __restrict__ x,
                                               const float* __restrict__ mrs, const float* __restrict__ g3,
                                               const float* __restrict__ b3, float* __restrict__ out) {
  int i4 = blockIdx.x * 256 + threadIdx.x;
  int b = i4 >> 20;
  int c = (i4 >> 12) & 255;
  int g = c >> 3;
  float mu = mrs[b * 32 + g], rs = mrs[128 + b * 32 + g];
  float ga = g3[c] * rs, be = b3[c] - mu * ga;
  float4 t = ((const float4*)t3)[i4];
  float4 xv = ((const float4*)x)[i4];
  float4 r;
  r.x = fmaxf(t.x * ga + be, 0.f) + xv.x;
  r.y = fmaxf(t.y * ga + be, 0.f) + xv.y;
  r.z = fmaxf(t.z * ga + be, 0.f) + xv.z;
  r.w = fmaxf(t.w * ga + be, 0.f) + xv.w;
  ((float4*)out)[i4] = r;
}

extern "C" void kernel_launch(void* const* d_in, const int* in_sizes, int n_in,
                              void* d_out, int out_size, void* d_ws, size_t ws_size,
                              hipStream_t stream) {
  const float* x    = (const float*)d_in[0];
  const float* w1   = (const float*)d_in[1];
  const float* g1   = (const float*)d_in[2];
  const float* b1   = (const float*)d_in[3];
  const float* woff = (const float*)d_in[4];
  const float* wdef = (const float*)d_in[5];
  const float* w3   = (const float*)d_in[6];
  const float* g3   = (const float*)d_in[7];
  const float* b3   = (const float*)d_in[8];
  float* ws = (float*)d_ws;

  float* xd   = ws;                 // 4,194,304
  float* offs = xd + 4194304;       // 1,179,648
  float* osum = offs + 1179648;     // 4,194,304
  float* t3   = osum + 4194304;     // 16,777,216
  float* mrs1 = t3 + 16777216;      // 256
  float* mrs2 = mrs1 + 256;         // 256
  float* w1T  = mrs2 + 256;         // 16,384
  float* w3T  = w1T + 16384;        // 16,384
  float* gap  = w3T + 16384;        // 36,864 (unused this round)
  float* ps   = gap + 36864;        // 2,048
  float* wofT = t3;                                  // alias (t3[0..10752))
  unsigned short* wBf = (unsigned short*)(t3 + 16384); // alias (73,728 B)
  float* ps2  = offs;                                // alias
  float* out  = (float*)d_out;

  hipLaunchKernelGGL(k_prep, dim3(144), dim3(256), 0, stream, w1, w3, wdef, woff, w1T, w3T, wBf, wofT);
  hipLaunchKernelGGL(k_conv1, dim3(256), dim3(512), 0, stream, x, w1T, xd);
  hipLaunchKernelGGL((k_gnstats_part<2, 4>), dim3(128, 4), dim3(256), 0, stream, xd, ps);
  hipLaunchKernelGGL(k_gnfin, dim3(1), dim3(128), 0, stream, ps, mrs1, 4, (float)(2 * HW));
  hipLaunchKernelGGL(k_gnapply1, dim3(4096), dim3(256), 0, stream, xd, mrs1, g1, b1);
  hipLaunchKernelGGL(k_off2, dim3(256, 2), dim3(256), 0, stream, xd, wofT, offs);
  hipLaunchKernelGGL(k_deform_mfma, dim3(1024), dim3(576), 0, stream, xd, offs, wBf, osum);
  hipLaunchKernelGGL(k_conv2b, dim3(1024), dim3(256), 0, stream, osum, w3T, t3, ps2);
  hipLaunchKernelGGL(k_gnfin2, dim3(1), dim3(128), 0, stream, ps2, mrs2);
  hipLaunchKernelGGL(k_final, dim3(16384), dim3(256), 0, stream, t3, x, mrs2, g3, b3, out);
}

// Round 7
// 231.963 us; speedup vs baseline: 1.6126x; 1.2430x over previous
//
#include <hip/hip_runtime.h>

// deformMP: B=4, Cc=256, ci=64, H=W=128, GN groups=32, eps=1e-5
// ws (floats): xd[4.19M] offs[1.18M] osum[4.19M] t3[16.78M] mrs1[256] mrs2[256]
//              w1T[16K] w3T[16K] (gap 36.9K) ps[2048]   (same 105.67 MB budget)
// aliases in t3 (dead until conv2b rewrites t3):
//   wofT = t3[0..10752)                     (read by k_off2)
//   wBf  = (ushort*)(t3 + 16384), 36864 bf16 (read by k_deform_mfma GEMM)
//   xdT  = t3 + 36864, 4.19M (NHWC xd)       (read by k_deform_mfma build)
//   ps2  = offs (offs dead after deform geometry)

#define HW 16384
#define WIDTH 128

typedef __attribute__((ext_vector_type(8))) short bf16x8;
typedef __attribute__((ext_vector_type(4))) float f32x4;

__device__ __forceinline__ unsigned short f2bf(float f) {
  unsigned int u = __float_as_uint(f);
  u = (u + 0x7fffu + ((u >> 16) & 1u)) >> 16;  // RNE
  return (unsigned short)u;
}

// ---- K0: weight repack ----
__global__ __launch_bounds__(256) void k_prep(const float* __restrict__ w1, const float* __restrict__ w3,
                                              const float* __restrict__ wdef, const float* __restrict__ woff,
                                              float* __restrict__ w1T, float* __restrict__ w3T,
                                              unsigned short* __restrict__ wBf, float* __restrict__ wofT) {
  int i = blockIdx.x * 256 + threadIdx.x;
  if (i < 16384) { int o = i >> 8, c = i & 255; w1T[c * 64 + o] = w1[i]; }    // w1 [64][256] -> [c][o]
  if (i < 16384) { int o = i >> 6, c = i & 63;  w3T[c * 256 + o] = w3[i]; }   // w3 [256][64] -> [c][o]
  if (i < 36864) {
    // B-fragments for mfma 16x16x32: [kt=18][n=4][lane=64][j=8], elem = W[K=kt*32+(lane>>4)*8+j][o=n*16+(lane&15)]
    // K index = tap*64 + c ; wdef [o][c][3][3]
    int j = i & 7;
    int lane = (i >> 3) & 63;
    int n = (i >> 9) & 3;
    int kt = i >> 11;
    int kk = kt * 32 + ((lane >> 4) << 3) + j;
    int tap = kk >> 6, c = kk & 63;
    int o = (n << 4) + (lane & 15);
    wBf[i] = f2bf(wdef[(size_t)o * 576 + c * 9 + tap]);
  }
  if (i < 10752) {                                                            // woff [18][64][3][3] -> [g][c][o*9+k] pad 84
    int g = i / 5376;
    int r = i - g * 5376;
    int c = r / 84;
    int p = r - c * 84;
    float v = 0.f;
    if (p < 81) {
      int o = p / 9, k = p - o * 9;
      v = woff[((size_t)((g * 9 + o) * 64 + c)) * 9 + k];
    }
    wofT[i] = v;
  }
}

// ---- K1: conv1x1 256->64. Block=512 thr (8 waves): wave w -> 8 outputs, lane -> 1 float4 ----
__global__ __launch_bounds__(512) void k_conv1(const float* __restrict__ x, const float* __restrict__ w1T,
                                               float* __restrict__ y) {
  int tid = threadIdx.x;
  int lane = tid & 63;
  int o0 = __builtin_amdgcn_readfirstlane(tid >> 6) * 8;
  int b = blockIdx.x >> 6;
  int hw = ((blockIdx.x & 63) << 8) + (lane << 2);
  const float* xb = x + (size_t)b * 256 * HW + hw;
  float acc[8][4];
#pragma unroll
  for (int i = 0; i < 8; i++)
#pragma unroll
    for (int j = 0; j < 4; j++) acc[i][j] = 0.f;
#pragma unroll 4
  for (int c = 0; c < 256; c++) {
    float4 xv = *(const float4*)(xb + (size_t)c * HW);
    const float* wp = w1T + c * 64 + o0;  // wave-uniform -> s_load
#pragma unroll
    for (int i = 0; i < 8; i++) {
      float w = wp[i];
      acc[i][0] += xv.x * w; acc[i][1] += xv.y * w;
      acc[i][2] += xv.z * w; acc[i][3] += xv.w * w;
    }
  }
  float* yb = y + (size_t)b * 64 * HW + hw;
#pragma unroll
  for (int i = 0; i < 8; i++)
    *(float4*)(yb + (size_t)(o0 + i) * HW) = make_float4(acc[i][0], acc[i][1], acc[i][2], acc[i][3]);
}

// ---- K2a: GN1 stats partials. grid (128, S) ----
template <int CPG, int S>
__global__ __launch_bounds__(256) void k_gnstats_part(const float* __restrict__ y, float* __restrict__ ps) {
  int bg = blockIdx.x, sl = blockIdx.y;
  const int N4 = CPG * HW / 4 / S;
  const float4* p = (const float4*)(y + (size_t)bg * CPG * HW) + (size_t)sl * N4;
  float s = 0.f, ss = 0.f;
  for (int i = threadIdx.x; i < N4; i += 256) {
    float4 v = p[i];
    s += v.x + v.y + v.z + v.w;
    ss += v.x * v.x + v.y * v.y + v.z * v.z + v.w * v.w;
  }
#pragma unroll
  for (int off = 32; off; off >>= 1) { s += __shfl_down(s, off); ss += __shfl_down(ss, off); }
  __shared__ float ls[4], lss[4];
  int wv = threadIdx.x >> 6;
  if ((threadIdx.x & 63) == 0) { ls[wv] = s; lss[wv] = ss; }
  __syncthreads();
  if (threadIdx.x == 0) {
    ps[(bg * S + sl) * 2] = ls[0] + ls[1] + ls[2] + ls[3];
    ps[(bg * S + sl) * 2 + 1] = lss[0] + lss[1] + lss[2] + lss[3];
  }
}

// ---- K2b: finalize GN1 stats ----
__global__ __launch_bounds__(128) void k_gnfin(const float* __restrict__ ps, float* __restrict__ mrs,
                                               int S, float n) {
  int bg = threadIdx.x;
  float s = 0.f, ss = 0.f;
  for (int sl = 0; sl < S; sl++) { s += ps[(bg * S + sl) * 2]; ss += ps[(bg * S + sl) * 2 + 1]; }
  float mu = s / n;
  float var = ss / n - mu * mu;
  mrs[bg] = mu;
  mrs[128 + bg] = rsqrtf(var + 1e-5f);
}

// ---- K3: apply GN1 + ReLU; write NCHW in place AND NHWC copy (xdT) via LDS transpose ----
__global__ __launch_bounds__(256) void k_gnapply_t(float* __restrict__ xd, float* __restrict__ xdT,
                                                   const float* __restrict__ mrs,
                                                   const float* __restrict__ g1, const float* __restrict__ b1) {
  __shared__ float tile[64 * 65];
  int tid = threadIdx.x;
  int b = blockIdx.x >> 8;            // 256 pixel-groups per batch
  int p0 = (blockIdx.x & 255) << 6;   // 64 pixels per block
  int lane = tid & 63;
  int w = tid >> 6;                   // 0..3
  const size_t bbase = (size_t)b * 64 * HW;
#pragma unroll
  for (int j = 0; j < 16; j++) {
    int c = w * 16 + j;
    int g = c >> 1;
    float mu = mrs[b * 32 + g], rs = mrs[128 + b * 32 + g];
    float ga = g1[c] * rs, be = b1[c] - mu * ga;
    float v = xd[bbase + (size_t)c * HW + p0 + lane];
    v = fmaxf(v * ga + be, 0.f);
    xd[bbase + (size_t)c * HW + p0 + lane] = v;   // NCHW (k_off2, residual)
    tile[lane * 65 + c] = v;
  }
  __syncthreads();
#pragma unroll
  for (int j = 0; j < 16; j++) {
    int px = w * 16 + j;
    xdT[((size_t)b * HW + p0 + px) * 64 + lane] = tile[px * 65 + lane];  // NHWC (deform gathers)
  }
}

// ---- K4: conv3x3 64->18 (offsets). grid (256, 2); weights staged in LDS ----
__global__ __launch_bounds__(256) void k_off2(const float* __restrict__ xd, const float* __restrict__ wofT,
                                              float* __restrict__ offs) {
  __shared__ float wl[64 * 84];
  int tid = threadIdx.x;
  int g = blockIdx.y;
  {
    const float4* src = (const float4*)(wofT + (size_t)g * 5376);
    float4* dst = (float4*)wl;
    for (int i = tid; i < 1344; i += 256) dst[i] = src[i];
  }
  __syncthreads();
  int b = blockIdx.x >> 6;
  int r0 = (blockIdx.x & 63) << 1;
  int y = r0 + (tid >> 7);
  int xc = tid & 127;
  const float* xb = xd + (size_t)b * 64 * HW;
  float acc[9];
#pragma unroll
  for (int o = 0; o < 9; o++) acc[o] = 0.f;
  for (int c = 0; c < 64; c++) {
    const float* pc = xb + (size_t)c * HW;
    float v[3][3];
#pragma unroll
    for (int ky = 0; ky < 3; ky++) {
      int yy = y + ky - 1;
      bool vy = (unsigned)yy < 128u;
#pragma unroll
      for (int kx = 0; kx < 3; kx++) {
        int xx = xc + kx - 1;
        bool vx = (unsigned)xx < 128u;
        v[ky][kx] = (vy && vx) ? pc[yy * WIDTH + xx] : 0.f;
      }
    }
    float wr[84];
    const float4* wc = (const float4*)(wl + c * 84);
#pragma unroll
    for (int q = 0; q < 21; q++) ((float4*)wr)[q] = wc[q];
#pragma unroll
    for (int o = 0; o < 9; o++)
#pragma unroll
      for (int k = 0; k < 9; k++) acc[o] += v[k / 3][k % 3] * wr[o * 9 + k];
  }
  float* op = offs + (size_t)b * 18 * HW + (size_t)(g * 9) * HW + y * WIDTH + xc;
#pragma unroll
  for (int o = 0; o < 9; o++) op[(size_t)o * HW] = acc[o];
}

// ---- K5: deform conv via bf16 MFMA, coalesced NHWC gathers.
// Block = 576 thr (9 waves), tile = 64 px. Build: wave = tap; geometry per-lane (pxl=lane);
// gather maps lane=(pair-sub q, ch-chunk): 4 pairs/iter, 4 coalesced 256B corner loads.
// A2 chunk-major in LDS: [kc=72][row=64 pad 65] 16B bf16x8 chunks (conflict-free GEMM reads).
// GEMM: waves 0..7 = (m-half, o-tile): D[64px][64o] = A @ W, + residual -> osum (NCHW).
__global__ __launch_bounds__(576, 5) void k_deform_mfma(const float* __restrict__ xd,
                                                        const float* __restrict__ xdT,
                                                        const float* __restrict__ offs,
                                                        const unsigned short* __restrict__ wBf,
                                                        float* __restrict__ osum) {
  __shared__ unsigned short A[72 * 65 * 8];  // 74,880 B, chunk-major
  int tid = threadIdx.x;
  int bb = blockIdx.x >> 8;
  int tile = blockIdx.x & 255;
  int px0 = tile << 6;
  const float* xb = xd + (size_t)bb * 64 * HW;
  const char* xbt = (const char*)(xdT + (size_t)bb * 64 * HW);
  int wave = tid >> 6;  // build: wave = tap (0..8)
  int lane = tid & 63;

  // ---- geometry for pair (pxl=lane, tap=wave), kept in regs ----
  float w00, w01, w10, w11;
  int a00, a01, a10, a11;
  {
    int px = px0 + lane;
    int y = px >> 7, xc = px & 127;
    const float* ob = offs + (size_t)bb * 18 * HW + px;
    float dy = ob[(size_t)(2 * wave) * HW];
    float dx = ob[(size_t)(2 * wave + 1) * HW];
    float py = (float)(y + wave / 3 - 1) + dy;
    float pxx = (float)(xc + wave % 3 - 1) + dx;
    float y0f = floorf(py), x0f = floorf(pxx);
    float ay = py - y0f, ax = pxx - x0f;
    int y0 = (int)y0f, x0 = (int)x0f;
    int y1i = y0 + 1, x1i = x0 + 1;
    float by0 = 1.f - ay, bx0 = 1.f - ax;
    bool vy0 = (unsigned)y0 < 128u, vy1 = (unsigned)y1i < 128u;
    bool vx0 = (unsigned)x0 < 128u, vx1 = (unsigned)x1i < 128u;
    w00 = (vy0 && vx0) ? by0 * bx0 : 0.f;
    w01 = (vy0 && vx1) ? by0 * ax : 0.f;
    w10 = (vy1 && vx0) ? ay * bx0 : 0.f;
    w11 = (vy1 && vx1) ? ay * ax : 0.f;
    int iy0 = min(max(y0, 0), 127), iy1 = min(max(y1i, 0), 127);
    int ix0 = min(max(x0, 0), 127), ix1 = min(max(x1i, 0), 127);
    a00 = (iy0 * WIDTH + ix0) << 8;  // byte offsets into NHWC (64ch * 4B = 256B per px)
    a01 = (iy0 * WIDTH + ix1) << 8;
    a10 = (iy1 * WIDTH + ix0) << 8;
    a11 = (iy1 * WIDTH + ix1) << 8;
  }

  // ---- gather phase: 4 pairs per iter; lane = (q = pair-sub, ch = chunk of 4 channels) ----
  {
    int q = lane >> 4;
    int ch = lane & 15;
    int co = ch << 4;                        // byte offset of channel chunk
    int kcb = wave * 8 + (ch >> 1);          // A2 chunk index
    int wbase = kcb * (65 * 16) + ((ch & 1) << 3);
#pragma unroll 2
    for (int g = 0; g < 16; ++g) {
      int src = 4 * g + q;
      float j0 = __shfl(w00, src), j1 = __shfl(w01, src);
      float j2 = __shfl(w10, src), j3 = __shfl(w11, src);
      int b0 = __shfl(a00, src), b1 = __shfl(a01, src);
      int b2 = __shfl(a10, src), b3 = __shfl(a11, src);
      float4 v0 = *(const float4*)(xbt + b0 + co);
      float4 v1 = *(const float4*)(xbt + b1 + co);
      float4 v2 = *(const float4*)(xbt + b2 + co);
      float4 v3 = *(const float4*)(xbt + b3 + co);
      float sx = j0 * v0.x + j1 * v1.x + j2 * v2.x + j3 * v3.x;
      float sy = j0 * v0.y + j1 * v1.y + j2 * v2.y + j3 * v3.y;
      float sz = j0 * v0.z + j1 * v1.z + j2 * v2.z + j3 * v3.z;
      float sw = j0 * v0.w + j1 * v1.w + j2 * v2.w + j3 * v3.w;
      unsigned int r0, r1;
      asm("v_cvt_pk_bf16_f32 %0, %1, %2" : "=v"(r0) : "v"(sx), "v"(sy));
      asm("v_cvt_pk_bf16_f32 %0, %1, %2" : "=v"(r1) : "v"(sz), "v"(sw));
      *(uint2*)((char*)A + wbase + src * 16) = make_uint2(r0, r1);
    }
  }
  __syncthreads();

  // ---- GEMM phase: waves 0..7 ----
  if (wave >= 8) return;
  int n = wave & 3;        // o-tile (16 outs)
  int mh = wave >> 2;      // m-half (32 px)
  int r0r = mh * 32 + (lane & 15);
  int kq = lane >> 4;
  const bf16x8* wp = (const bf16x8*)wBf;
  f32x4 acc0 = {0.f, 0.f, 0.f, 0.f};
  f32x4 acc1 = {0.f, 0.f, 0.f, 0.f};
#pragma unroll 3
  for (int kt = 0; kt < 18; kt++) {
    bf16x8 bk = wp[(kt * 4 + n) * 64 + lane];  // L2-hot, per-lane contiguous 16B
    int kc = kt * 4 + kq;
    bf16x8 a0 = *(const bf16x8*)((const char*)A + (kc * 65 + r0r) * 16);
    bf16x8 a1 = *(const bf16x8*)((const char*)A + (kc * 65 + r0r + 16) * 16);
    acc0 = __builtin_amdgcn_mfma_f32_16x16x32_bf16(a0, bk, acc0, 0, 0, 0);
    acc1 = __builtin_amdgcn_mfma_f32_16x16x32_bf16(a1, bk, acc1, 0, 0, 0);
  }
  // epilogue: D col = lane&15 (o), row = (lane>>4)*4 + r (px); + residual
  int o = n * 16 + (lane & 15);
  int prow = mh * 32 + ((lane >> 4) << 2);
  float* op = osum + (size_t)bb * 64 * HW + (size_t)o * HW + px0 + prow;
  const float* xr = xb + (size_t)o * HW + px0 + prow;
#pragma unroll
  for (int r = 0; r < 4; r++) {
    op[r] = acc0[r] + xr[r];
    op[16 + r] = acc1[r] + xr[16 + r];
  }
}

// ---- K6: conv1x1 64->256 + fused GN2 partial stats. Block = 64 px, all 256 outs ----
__global__ __launch_bounds__(256) void k_conv2b(const float* __restrict__ osum, const float* __restrict__ w3T,
                                                float* __restrict__ t3, float* __restrict__ ps2) {
  __shared__ float wl[64 * 256];
  int tid = threadIdx.x;
  {
    const float4* src = (const float4*)w3T;
    float4* dst = (float4*)wl;
#pragma unroll
    for (int i = 0; i < 16; i++) dst[tid + i * 256] = src[tid + i * 256];
  }
  __syncthreads();
  int lane = tid & 63;
  int w = __builtin_amdgcn_readfirstlane(tid >> 6);
  int b = blockIdx.x >> 8;
  int chunk = blockIdx.x & 255;
  int px0 = chunk << 6;
  const float* ib = osum + (size_t)b * 64 * HW + px0 + lane;
  float acc[64];
#pragma unroll
  for (int o = 0; o < 64; o++) acc[o] = 0.f;
#pragma unroll 2
  for (int c = 0; c < 64; c++) {
    float v = ib[(size_t)c * HW];
    const float4* wc = (const float4*)(wl + c * 256 + w * 64);
#pragma unroll
    for (int q = 0; q < 16; q++) {
      float4 u = wc[q];
      acc[4 * q + 0] += v * u.x;
      acc[4 * q + 1] += v * u.y;
      acc[4 * q + 2] += v * u.z;
      acc[4 * q + 3] += v * u.w;
    }
  }
  float* tb = t3 + (size_t)b * 256 * HW + (size_t)(w * 64) * HW + px0 + lane;
#pragma unroll
  for (int o = 0; o < 64; o++) tb[(size_t)o * HW] = acc[o];
  float s[8], ss[8];
#pragma unroll
  for (int g = 0; g < 8; g++) {
    float a = 0.f, q = 0.f;
#pragma unroll
    for (int i = 0; i < 8; i++) { float v = acc[g * 8 + i]; a += v; q += v * v; }
    s[g] = a; ss[g] = q;
  }
#pragma unroll
  for (int g = 0; g < 8; g++) {
#pragma unroll
    for (int off = 32; off; off >>= 1) { s[g] += __shfl_down(s[g], off); ss[g] += __shfl_down(ss[g], off); }
  }
  if (lane == 0) {
#pragma unroll
    for (int g = 0; g < 8; g++) {
      int bg = b * 32 + w * 8 + g;
      ps2[(bg * 256 + chunk) * 2] = s[g];
      ps2[(bg * 256 + chunk) * 2 + 1] = ss[g];
    }
  }
}

// ---- K7: finalize GN2 stats ----
__global__ __launch_bounds__(128) void k_gnfin2(const float* __restrict__ ps2, float* __restrict__ mrs) {
  int bg = threadIdx.x;
  float s = 0.f, ss = 0.f;
  for (int ch = 0; ch < 256; ch++) { s += ps2[(bg * 256 + ch) * 2]; ss += ps2[(bg * 256 + ch) * 2 + 1]; }
  const float n = 131072.f;
  float mu = s / n;
  float var = ss / n - mu * mu;
  mrs[bg] = mu;
  mrs[128 + bg] = rsqrtf(var + 1e-5f);
}

// ---- K8: out = relu(gn2(t3)) + x ----
__global__ __launch_bounds__(256) void k_final(const float* __restrict__ t3, const float* __restrict__ x,
                                               const float* __restrict__ mrs, const float* __restrict__ g3,
                                               const float* __restrict__ b3, float* __restrict__ out) {
  int i4 = blockIdx.x * 256 + threadIdx.x;
  int b = i4 >> 20;
  int c = (i4 >> 12) & 255;
  int g = c >> 3;
  float mu = mrs[b * 32 + g], rs = mrs[128 + b * 32 + g];
  float ga = g3[c] * rs, be = b3[c] - mu * ga;
  float4 t = ((const float4*)t3)[i4];
  float4 xv = ((const float4*)x)[i4];
  float4 r;
  r.x = fmaxf(t.x * ga + be, 0.f) + xv.x;
  r.y = fmaxf(t.y * ga + be, 0.f) + xv.y;
  r.z = fmaxf(t.z * ga + be, 0.f) + xv.z;
  r.w = fmaxf(t.w * ga + be, 0.f) + xv.w;
  ((float4*)out)[i4] = r;
}

extern "C" void kernel_launch(void* const* d_in, const int* in_sizes, int n_in,
                              void* d_out, int out_size, void* d_ws, size_t ws_size,
                              hipStream_t stream) {
  const float* x    = (const float*)d_in[0];
  const float* w1   = (const float*)d_in[1];
  const float* g1   = (const float*)d_in[2];
  const float* b1   = (const float*)d_in[3];
  const float* woff = (const float*)d_in[4];
  const float* wdef = (const float*)d_in[5];
  const float* w3   = (const float*)d_in[6];
  const float* g3   = (const float*)d_in[7];
  const float* b3   = (const float*)d_in[8];
  float* ws = (float*)d_ws;

  float* xd   = ws;                 // 4,194,304
  float* offs = xd + 4194304;       // 1,179,648
  float* osum = offs + 1179648;     // 4,194,304
  float* t3   = osum + 4194304;     // 16,777,216
  float* mrs1 = t3 + 16777216;      // 256
  float* mrs2 = mrs1 + 256;         // 256
  float* w1T  = mrs2 + 256;         // 16,384
  float* w3T  = w1T + 16384;        // 16,384
  float* gap  = w3T + 16384;        // 36,864 (unused)
  float* ps   = gap + 36864;        // 2,048
  float* wofT = t3;                                    // alias (t3[0..10752))
  unsigned short* wBf = (unsigned short*)(t3 + 16384); // alias (73,728 B)
  float* xdT  = t3 + 36864;                            // alias (4.19M, NHWC)
  float* ps2  = offs;                                  // alias
  float* out  = (float*)d_out;

  hipLaunchKernelGGL(k_prep, dim3(144), dim3(256), 0, stream, w1, w3, wdef, woff, w1T, w3T, wBf, wofT);
  hipLaunchKernelGGL(k_conv1, dim3(256), dim3(512), 0, stream, x, w1T, xd);
  hipLaunchKernelGGL((k_gnstats_part<2, 4>), dim3(128, 4), dim3(256), 0, stream, xd, ps);
  hipLaunchKernelGGL(k_gnfin, dim3(1), dim3(128), 0, stream, ps, mrs1, 4, (float)(2 * HW));
  hipLaunchKernelGGL(k_gnapply_t, dim3(1024), dim3(256), 0, stream, xd, xdT, mrs1, g1, b1);
  hipLaunchKernelGGL(k_off2, dim3(256, 2), dim3(256), 0, stream, xd, wofT, offs);
  hipLaunchKernelGGL(k_deform_mfma, dim3(1024), dim3(576), 0, stream, xd, xdT, offs, wBf, osum);
  hipLaunchKernelGGL(k_conv2b, dim3(1024), dim3(256), 0, stream, osum, w3T, t3, ps2);
  hipLaunchKernelGGL(k_gnfin2, dim3(1), dim3(128), 0, stream, ps2, mrs2);
  hipLaunchKernelGGL(k_final, dim3(16384), dim3(256), 0, stream, t3, x, mrs2, g3, b3, out);
}

// Round 8
// 202.151 us; speedup vs baseline: 1.8505x; 1.1475x over previous
//
#include <hip/hip_runtime.h>

// deformMP: B=4, Cc=256, ci=64, H=W=128, GN groups=32, eps=1e-5
// ws (floats): xd[4.19M] offs[1.18M] osum[4.19M] t3[16.78M] mrs1[256] mrs2[256]
//              w1T[16K] w3T[16K] gap[36.9K: wofBf(9.2K) ps(16.4K)] (105.67 MB budget)
// aliases in t3 (dead until conv2b rewrites t3):
//   wBf = (ushort*)(t3 + 16384), 36864 bf16 (deform GEMM weights)
//   xdT = t3 + 36864, 4.19M (NHWC xd; read by k_off_mfma + k_deform_mfma)
//   ps2 = offs (offs dead after deform)

#define HW 16384
#define WIDTH 128

typedef __attribute__((ext_vector_type(8))) short bf16x8;
typedef __attribute__((ext_vector_type(4))) float f32x4;

__device__ __forceinline__ unsigned short f2bf(float f) {
  unsigned int u = __float_as_uint(f);
  u = (u + 0x7fffu + ((u >> 16) & 1u)) >> 16;  // RNE
  return (unsigned short)u;
}

// ---- K0: weight repack ----
__global__ __launch_bounds__(256) void k_prep(const float* __restrict__ w1, const float* __restrict__ w3,
                                              const float* __restrict__ wdef, const float* __restrict__ woff,
                                              float* __restrict__ w1T, float* __restrict__ w3T,
                                              unsigned short* __restrict__ wBf,
                                              unsigned short* __restrict__ wofBf) {
  int i = blockIdx.x * 256 + threadIdx.x;
  if (i < 16384) { int o = i >> 8, c = i & 255; w1T[c * 64 + o] = w1[i]; }    // w1 [64][256] -> [c][o]
  if (i < 16384) { int o = i >> 6, c = i & 63;  w3T[c * 256 + o] = w3[i]; }   // w3 [256][64] -> [c][o]
  if (i < 36864) {
    // deform B-frags: [kt=18][n=4][lane=64][j=8]; elem = Wd[K=kt*32+(lane>>4)*8+j][o=n*16+(lane&15)]
    // K = tap*64 + c ; wdef [o][c][3][3]
    int j = i & 7;
    int lane = (i >> 3) & 63;
    int n = (i >> 9) & 3;
    int kt = i >> 11;
    int kk = kt * 32 + ((lane >> 4) << 3) + j;
    int tap = kk >> 6, c = kk & 63;
    int o = (n << 4) + (lane & 15);
    wBf[i] = f2bf(wdef[(size_t)o * 576 + c * 9 + tap]);
  }
  if (i < 18432) {
    // offs-conv B-frags: [kt=18][n=2][lane=64][j=8]; o = n*16+(lane&15), zero-pad o>=18
    // K = tap*64 + c ; woff [18][64][3][3]
    int j = i & 7;
    int lane = (i >> 3) & 63;
    int n = (i >> 9) & 1;
    int kt = i >> 10;
    int kk = kt * 32 + ((lane >> 4) << 3) + j;
    int tap = kk >> 6, c = kk & 63;
    int o = (n << 4) + (lane & 15);
    wofBf[i] = (o < 18) ? f2bf(woff[((size_t)(o * 64 + c)) * 9 + tap]) : (unsigned short)0;
  }
}

// ---- K1: conv1x1 256->64 + fused GN1 partial stats.
// Block=512 thr (8 waves): wave w -> 8 outs (= 4 GN groups, CPG=2), lane -> 1 float4 of px.
__global__ __launch_bounds__(512) void k_conv1(const float* __restrict__ x, const float* __restrict__ w1T,
                                               float* __restrict__ y, float* __restrict__ ps) {
  int tid = threadIdx.x;
  int lane = tid & 63;
  int o0 = __builtin_amdgcn_readfirstlane(tid >> 6) * 8;
  int b = blockIdx.x >> 6;
  int chunk = blockIdx.x & 63;
  int hw = (chunk << 8) + (lane << 2);
  const float* xb = x + (size_t)b * 256 * HW + hw;
  float acc[8][4];
#pragma unroll
  for (int i = 0; i < 8; i++)
#pragma unroll
    for (int j = 0; j < 4; j++) acc[i][j] = 0.f;
#pragma unroll 4
  for (int c = 0; c < 256; c++) {
    float4 xv = *(const float4*)(xb + (size_t)c * HW);
    const float* wp = w1T + c * 64 + o0;  // wave-uniform -> s_load
#pragma unroll
    for (int i = 0; i < 8; i++) {
      float w = wp[i];
      acc[i][0] += xv.x * w; acc[i][1] += xv.y * w;
      acc[i][2] += xv.z * w; acc[i][3] += xv.w * w;
    }
  }
  float* yb = y + (size_t)b * 64 * HW + hw;
#pragma unroll
  for (int i = 0; i < 8; i++)
    *(float4*)(yb + (size_t)(o0 + i) * HW) = make_float4(acc[i][0], acc[i][1], acc[i][2], acc[i][3]);
  // GN1 partials: wave's 8 chans = 4 groups of 2 (aligned since o0 % 8 == 0)
  float gs[4], gss[4];
#pragma unroll
  for (int k = 0; k < 4; k++) {
    float a = 0.f, q = 0.f;
#pragma unroll
    for (int t = 0; t < 2; t++)
#pragma unroll
      for (int j = 0; j < 4; j++) { float v = acc[2 * k + t][j]; a += v; q += v * v; }
    gs[k] = a; gss[k] = q;
  }
#pragma unroll
  for (int k = 0; k < 4; k++) {
#pragma unroll
    for (int off = 32; off; off >>= 1) { gs[k] += __shfl_down(gs[k], off); gss[k] += __shfl_down(gss[k], off); }
  }
  if (lane == 0) {
    int g0 = o0 >> 1;
#pragma unroll
    for (int k = 0; k < 4; k++) {
      int bg = b * 32 + g0 + k;
      ps[(bg * 64 + chunk) * 2] = gs[k];
      ps[(bg * 64 + chunk) * 2 + 1] = gss[k];
    }
  }
}

// ---- K2b: finalize GN stats (generic S-chunk) ----
__global__ __launch_bounds__(128) void k_gnfin(const float* __restrict__ ps, float* __restrict__ mrs,
                                               int S, float n) {
  int bg = threadIdx.x;
  float s = 0.f, ss = 0.f;
  for (int sl = 0; sl < S; sl++) { s += ps[(bg * S + sl) * 2]; ss += ps[(bg * S + sl) * 2 + 1]; }
  float mu = s / n;
  float var = ss / n - mu * mu;
  mrs[bg] = mu;
  mrs[128 + bg] = rsqrtf(var + 1e-5f);
}

// ---- K3: apply GN1 + ReLU; read NCHW xd, write NHWC xdT via LDS transpose ----
__global__ __launch_bounds__(256) void k_gnapply_t(const float* __restrict__ xd, float* __restrict__ xdT,
                                                   const float* __restrict__ mrs,
                                                   const float* __restrict__ g1, const float* __restrict__ b1) {
  __shared__ float tile[64 * 65];
  int tid = threadIdx.x;
  int b = blockIdx.x >> 8;            // 256 pixel-groups per batch
  int p0 = (blockIdx.x & 255) << 6;   // 64 pixels per block
  int lane = tid & 63;
  int w = tid >> 6;                   // 0..3
  const size_t bbase = (size_t)b * 64 * HW;
#pragma unroll
  for (int j = 0; j < 16; j++) {
    int c = w * 16 + j;
    int g = c >> 1;
    float mu = mrs[b * 32 + g], rs = mrs[128 + b * 32 + g];
    float ga = g1[c] * rs, be = b1[c] - mu * ga;
    float v = xd[bbase + (size_t)c * HW + p0 + lane];
    v = fmaxf(v * ga + be, 0.f);
    tile[lane * 65 + c] = v;
  }
  __syncthreads();
#pragma unroll
  for (int j = 0; j < 16; j++) {
    int px = w * 16 + j;
    xdT[((size_t)b * HW + p0 + px) * 64 + lane] = tile[px * 65 + lane];  // NHWC
  }
}

// ---- K4: offsets conv3x3 64->18 via bf16 MFMA (fixed-tap im2col GEMM).
// Block = 576 thr (9 waves), tile = 64 px. Build: wave=tap, lane=(q,ch), 1 coalesced
// 256B load/iter, zero-fill at borders. A chunk-major [72][65][16B]. GEMM: waves 0..7
// = (mh 0..3, n 0..1): D[16px][16o], K=576; store o<18 to offs (NCHW).
__global__ __launch_bounds__(576, 2) void k_off_mfma(const float* __restrict__ xdT,
                                                     const unsigned short* __restrict__ wofBf,
                                                     float* __restrict__ offs) {
  __shared__ unsigned short A[72 * 65 * 8];  // 74,880 B
  int tid = threadIdx.x;
  int bb = blockIdx.x >> 8;
  int px0 = (blockIdx.x & 255) << 6;
  const char* xbt = (const char*)(xdT + (size_t)bb * 64 * HW);
  int wave = tid >> 6;  // tap 0..8
  int lane = tid & 63;
  {
    int q = lane >> 4;
    int ch = lane & 15;
    int co = ch << 4;
    int kcb = wave * 8 + (ch >> 1);
    int wbase = kcb * (65 * 16) + ((ch & 1) << 3);
    int ky = wave / 3 - 1, kx = wave % 3 - 1;
#pragma unroll 2
    for (int g = 0; g < 16; ++g) {
      int src = 4 * g + q;
      int px = px0 + src;
      int sy = (px >> 7) + ky;
      int sx = (px & 127) + kx;
      bool valid = ((unsigned)sy < 128u) && ((unsigned)sx < 128u);
      float4 v = make_float4(0.f, 0.f, 0.f, 0.f);
      if (valid) v = *(const float4*)(xbt + (((sy << 7) + sx) << 8) + co);
      unsigned int r0, r1;
      asm("v_cvt_pk_bf16_f32 %0, %1, %2" : "=v"(r0) : "v"(v.x), "v"(v.y));
      asm("v_cvt_pk_bf16_f32 %0, %1, %2" : "=v"(r1) : "v"(v.z), "v"(v.w));
      *(uint2*)((char*)A + wbase + src * 16) = make_uint2(r0, r1);
    }
  }
  __syncthreads();
  if (wave >= 8) return;
  int n = wave & 1;        // o-tile
  int mh = wave >> 1;      // m-tile (16 px)
  int r0r = mh * 16 + (lane & 15);
  int kq = lane >> 4;
  const bf16x8* wp = (const bf16x8*)wofBf;
  f32x4 acc = {0.f, 0.f, 0.f, 0.f};
#pragma unroll 3
  for (int kt = 0; kt < 18; kt++) {
    bf16x8 bk = wp[(kt * 2 + n) * 64 + lane];
    int kc = kt * 4 + kq;
    bf16x8 a0 = *(const bf16x8*)((const char*)A + (kc * 65 + r0r) * 16);
    acc = __builtin_amdgcn_mfma_f32_16x16x32_bf16(a0, bk, acc, 0, 0, 0);
  }
  int o = n * 16 + (lane & 15);
  if (o < 18) {
    int prow = mh * 16 + ((lane >> 4) << 2);
    float* op = offs + (size_t)bb * 18 * HW + (size_t)o * HW + px0 + prow;
#pragma unroll
    for (int r = 0; r < 4; r++) op[r] = acc[r];
  }
}

// ---- K5: deform conv via bf16 MFMA, coalesced NHWC gathers; residual from xdT ----
__global__ __launch_bounds__(576, 2) void k_deform_mfma(const float* __restrict__ xdT,
                                                        const float* __restrict__ offs,
                                                        const unsigned short* __restrict__ wBf,
                                                        float* __restrict__ osum) {
  __shared__ unsigned short A[72 * 65 * 8];  // 74,880 B, chunk-major
  int tid = threadIdx.x;
  int bb = blockIdx.x >> 8;
  int px0 = (blockIdx.x & 255) << 6;
  const float* xtf = xdT + (size_t)bb * 64 * HW;
  const char* xbt = (const char*)xtf;
  int wave = tid >> 6;  // build: wave = tap (0..8)
  int lane = tid & 63;

  // geometry for pair (pxl=lane, tap=wave)
  float w00, w01, w10, w11;
  int a00, a01, a10, a11;
  {
    int px = px0 + lane;
    int y = px >> 7, xc = px & 127;
    const float* ob = offs + (size_t)bb * 18 * HW + px;
    float dy = ob[(size_t)(2 * wave) * HW];
    float dx = ob[(size_t)(2 * wave + 1) * HW];
    float py = (float)(y + wave / 3 - 1) + dy;
    float pxx = (float)(xc + wave % 3 - 1) + dx;
    float y0f = floorf(py), x0f = floorf(pxx);
    float ay = py - y0f, ax = pxx - x0f;
    int y0 = (int)y0f, x0 = (int)x0f;
    int y1i = y0 + 1, x1i = x0 + 1;
    float by0 = 1.f - ay, bx0 = 1.f - ax;
    bool vy0 = (unsigned)y0 < 128u, vy1 = (unsigned)y1i < 128u;
    bool vx0 = (unsigned)x0 < 128u, vx1 = (unsigned)x1i < 128u;
    w00 = (vy0 && vx0) ? by0 * bx0 : 0.f;
    w01 = (vy0 && vx1) ? by0 * ax : 0.f;
    w10 = (vy1 && vx0) ? ay * bx0 : 0.f;
    w11 = (vy1 && vx1) ? ay * ax : 0.f;
    int iy0 = min(max(y0, 0), 127), iy1 = min(max(y1i, 0), 127);
    int ix0 = min(max(x0, 0), 127), ix1 = min(max(x1i, 0), 127);
    a00 = (iy0 * WIDTH + ix0) << 8;
    a01 = (iy0 * WIDTH + ix1) << 8;
    a10 = (iy1 * WIDTH + ix0) << 8;
    a11 = (iy1 * WIDTH + ix1) << 8;
  }

  // gather: 4 pairs/iter; lane = (q = pair-sub, ch = 4-channel chunk)
  {
    int q = lane >> 4;
    int ch = lane & 15;
    int co = ch << 4;
    int kcb = wave * 8 + (ch >> 1);
    int wbase = kcb * (65 * 16) + ((ch & 1) << 3);
#pragma unroll 2
    for (int g = 0; g < 16; ++g) {
      int src = 4 * g + q;
      float j0 = __shfl(w00, src), j1 = __shfl(w01, src);
      float j2 = __shfl(w10, src), j3 = __shfl(w11, src);
      int b0 = __shfl(a00, src), b1 = __shfl(a01, src);
      int b2 = __shfl(a10, src), b3 = __shfl(a11, src);
      float4 v0 = *(const float4*)(xbt + b0 + co);
      float4 v1 = *(const float4*)(xbt + b1 + co);
      float4 v2 = *(const float4*)(xbt + b2 + co);
      float4 v3 = *(const float4*)(xbt + b3 + co);
      float sx = j0 * v0.x + j1 * v1.x + j2 * v2.x + j3 * v3.x;
      float sy = j0 * v0.y + j1 * v1.y + j2 * v2.y + j3 * v3.y;
      float sz = j0 * v0.z + j1 * v1.z + j2 * v2.z + j3 * v3.z;
      float sw = j0 * v0.w + j1 * v1.w + j2 * v2.w + j3 * v3.w;
      unsigned int r0, r1;
      asm("v_cvt_pk_bf16_f32 %0, %1, %2" : "=v"(r0) : "v"(sx), "v"(sy));
      asm("v_cvt_pk_bf16_f32 %0, %1, %2" : "=v"(r1) : "v"(sz), "v"(sw));
      *(uint2*)((char*)A + wbase + src * 16) = make_uint2(r0, r1);
    }
  }
  __syncthreads();

  // GEMM: waves 0..7 = (m-half, o-tile)
  if (wave >= 8) return;
  int n = wave & 3;
  int mh = wave >> 2;
  int r0r = mh * 32 + (lane & 15);
  int kq = lane >> 4;
  const bf16x8* wp = (const bf16x8*)wBf;
  f32x4 acc0 = {0.f, 0.f, 0.f, 0.f};
  f32x4 acc1 = {0.f, 0.f, 0.f, 0.f};
#pragma unroll 3
  for (int kt = 0; kt < 18; kt++) {
    bf16x8 bk = wp[(kt * 4 + n) * 64 + lane];
    int kc = kt * 4 + kq;
    bf16x8 a0 = *(const bf16x8*)((const char*)A + (kc * 65 + r0r) * 16);
    bf16x8 a1 = *(const bf16x8*)((const char*)A + (kc * 65 + r0r + 16) * 16);
    acc0 = __builtin_amdgcn_mfma_f32_16x16x32_bf16(a0, bk, acc0, 0, 0, 0);
    acc1 = __builtin_amdgcn_mfma_f32_16x16x32_bf16(a1, bk, acc1, 0, 0, 0);
  }
  // epilogue: D col = lane&15 (o), row = (lane>>4)*4 + r (px); residual from xdT (NHWC)
  int o = n * 16 + (lane & 15);
  int prow = mh * 32 + ((lane >> 4) << 2);
  int pbase = px0 + prow;
  float* op = osum + (size_t)bb * 64 * HW + (size_t)o * HW + pbase;
#pragma unroll
  for (int r = 0; r < 4; r++) {
    op[r] = acc0[r] + xtf[(size_t)(pbase + r) * 64 + o];
    op[16 + r] = acc1[r] + xtf[(size_t)(pbase + 16 + r) * 64 + o];
  }
}

// ---- K6: conv1x1 64->256 + fused GN2 partial stats. Block = 64 px, all 256 outs ----
__global__ __launch_bounds__(256) void k_conv2b(const float* __restrict__ osum, const float* __restrict__ w3T,
                                                float* __restrict__ t3, float* __restrict__ ps2) {
  __shared__ float wl[64 * 256];
  int tid = threadIdx.x;
  {
    const float4* src = (const float4*)w3T;
    float4* dst = (float4*)wl;
#pragma unroll
    for (int i = 0; i < 16; i++) dst[tid + i * 256] = src[tid + i * 256];
  }
  __syncthreads();
  int lane = tid & 63;
  int w = __builtin_amdgcn_readfirstlane(tid >> 6);
  int b = blockIdx.x >> 8;
  int chunk = blockIdx.x & 255;
  int px0 = chunk << 6;
  const float* ib = osum + (size_t)b * 64 * HW + px0 + lane;
  float acc[64];
#pragma unroll
  for (int o = 0; o < 64; o++) acc[o] = 0.f;
#pragma unroll 2
  for (int c = 0; c < 64; c++) {
    float v = ib[(size_t)c * HW];
    const float4* wc = (const float4*)(wl + c * 256 + w * 64);
#pragma unroll
    for (int q = 0; q < 16; q++) {
      float4 u = wc[q];
      acc[4 * q + 0] += v * u.x;
      acc[4 * q + 1] += v * u.y;
      acc[4 * q + 2] += v * u.z;
      acc[4 * q + 3] += v * u.w;
    }
  }
  float* tb = t3 + (size_t)b * 256 * HW + (size_t)(w * 64) * HW + px0 + lane;
#pragma unroll
  for (int o = 0; o < 64; o++) tb[(size_t)o * HW] = acc[o];
  float s[8], ss[8];
#pragma unroll
  for (int g = 0; g < 8; g++) {
    float a = 0.f, q = 0.f;
#pragma unroll
    for (int i = 0; i < 8; i++) { float v = acc[g * 8 + i]; a += v; q += v * v; }
    s[g] = a; ss[g] = q;
  }
#pragma unroll
  for (int g = 0; g < 8; g++) {
#pragma unroll
    for (int off = 32; off; off >>= 1) { s[g] += __shfl_down(s[g], off); ss[g] += __shfl_down(ss[g], off); }
  }
  if (lane == 0) {
#pragma unroll
    for (int g = 0; g < 8; g++) {
      int bg = b * 32 + w * 8 + g;
      ps2[(bg * 256 + chunk) * 2] = s[g];
      ps2[(bg * 256 + chunk) * 2 + 1] = ss[g];
    }
  }
}

// ---- K7: finalize GN2 stats ----
__global__ __launch_bounds__(128) void k_gnfin2(const float* __restrict__ ps2, float* __restrict__ mrs) {
  int bg = threadIdx.x;
  float s = 0.f, ss = 0.f;
  for (int ch = 0; ch < 256; ch++) { s += ps2[(bg * 256 + ch) * 2]; ss += ps2[(bg * 256 + ch) * 2 + 1]; }
  const float n = 131072.f;
  float mu = s / n;
  float var = ss / n - mu * mu;
  mrs[bg] = mu;
  mrs[128 + bg] = rsqrtf(var + 1e-5f);
}

// ---- K8: out = relu(gn2(t3)) + x ----
__global__ __launch_bounds__(256) void k_final(const float* __restrict__ t3, const float* __restrict__ x,
                                               const float* __restrict__ mrs, const float* __restrict__ g3,
                                               const float* __restrict__ b3, float* __restrict__ out) {
  int i4 = blockIdx.x * 256 + threadIdx.x;
  int b = i4 >> 20;
  int c = (i4 >> 12) & 255;
  int g = c >> 3;
  float mu = mrs[b * 32 + g], rs = mrs[128 + b * 32 + g];
  float ga = g3[c] * rs, be = b3[c] - mu * ga;
  float4 t = ((const float4*)t3)[i4];
  float4 xv = ((const float4*)x)[i4];
  float4 r;
  r.x = fmaxf(t.x * ga + be, 0.f) + xv.x;
  r.y = fmaxf(t.y * ga + be, 0.f) + xv.y;
  r.z = fmaxf(t.z * ga + be, 0.f) + xv.z;
  r.w = fmaxf(t.w * ga + be, 0.f) + xv.w;
  ((float4*)out)[i4] = r;
}

extern "C" void kernel_launch(void* const* d_in, const int* in_sizes, int n_in,
                              void* d_out, int out_size, void* d_ws, size_t ws_size,
                              hipStream_t stream) {
  const float* x    = (const float*)d_in[0];
  const float* w1   = (const float*)d_in[1];
  const float* g1   = (const float*)d_in[2];
  const float* b1   = (const float*)d_in[3];
  const float* woff = (const float*)d_in[4];
  const float* wdef = (const float*)d_in[5];
  const float* w3   = (const float*)d_in[6];
  const float* g3   = (const float*)d_in[7];
  const float* b3   = (const float*)d_in[8];
  float* ws = (float*)d_ws;

  float* xd   = ws;                 // 4,194,304
  float* offs = xd + 4194304;       // 1,179,648
  float* osum = offs + 1179648;     // 4,194,304
  float* t3   = osum + 4194304;     // 16,777,216
  float* mrs1 = t3 + 16777216;      // 256
  float* mrs2 = mrs1 + 256;         // 256
  float* w1T  = mrs2 + 256;         // 16,384
  float* w3T  = w1T + 16384;        // 16,384
  float* gap  = w3T + 16384;        // 36,864: wofBf(9,216 fl) + ps(16,384 fl)
  unsigned short* wofBf = (unsigned short*)gap;
  float* ps   = gap + 9216;
  unsigned short* wBf = (unsigned short*)(t3 + 16384); // alias (73,728 B)
  float* xdT  = t3 + 36864;                            // alias (4.19M, NHWC)
  float* ps2  = offs;                                  // alias
  float* out  = (float*)d_out;

  hipLaunchKernelGGL(k_prep, dim3(144), dim3(256), 0, stream, w1, w3, wdef, woff, w1T, w3T, wBf, wofBf);
  hipLaunchKernelGGL(k_conv1, dim3(256), dim3(512), 0, stream, x, w1T, xd, ps);
  hipLaunchKernelGGL(k_gnfin, dim3(1), dim3(128), 0, stream, ps, mrs1, 64, (float)(2 * HW));
  hipLaunchKernelGGL(k_gnapply_t, dim3(1024), dim3(256), 0, stream, xd, xdT, mrs1, g1, b1);
  hipLaunchKernelGGL(k_off_mfma, dim3(1024), dim3(576), 0, stream, xdT, wofBf, offs);
  hipLaunchKernelGGL(k_deform_mfma, dim3(1024), dim3(576), 0, stream, xdT, offs, wBf, osum);
  hipLaunchKernelGGL(k_conv2b, dim3(1024), dim3(256), 0, stream, osum, w3T, t3, ps2);
  hipLaunchKernelGGL(k_gnfin2, dim3(1), dim3(128), 0, stream, ps2, mrs2);
  hipLaunchKernelGGL(k_final, dim3(16384), dim3(256), 0, stream, t3, x, mrs2, g3, b3, out);
}

// Round 9
// 170.570 us; speedup vs baseline: 2.1931x; 1.1851x over previous
//
#include <hip/hip_runtime.h>

// deformMP: B=4, Cc=256, ci=64, H=W=128, GN groups=32, eps=1e-5
// ws (floats, no aliases, total ~72.7 MB):
//   xd[4.19M] offs[1.18M] xdT[4.19M] t3bf[8.39M fl-equiv (ushort)] mrs1[256] mrs2[256]
//   w1T[16K] wBf[18.4K] wofBf[9.2K] w3Bf[16.4K] ps[16.4K] ps2[131K]

#define HW 16384
#define WIDTH 128

typedef __attribute__((ext_vector_type(8))) short bf16x8;
typedef __attribute__((ext_vector_type(4))) float f32x4;

__device__ __forceinline__ unsigned short f2bf(float f) {
  unsigned int u = __float_as_uint(f);
  u = (u + 0x7fffu + ((u >> 16) & 1u)) >> 16;  // RNE
  return (unsigned short)u;
}

// ---- K0: weight repack ----
__global__ __launch_bounds__(256) void k_prep(const float* __restrict__ w1, const float* __restrict__ w3,
                                              const float* __restrict__ wdef, const float* __restrict__ woff,
                                              float* __restrict__ w1T,
                                              unsigned short* __restrict__ wBf,
                                              unsigned short* __restrict__ wofBf,
                                              unsigned short* __restrict__ w3Bf) {
  int i = blockIdx.x * 256 + threadIdx.x;
  if (i < 16384) { int o = i >> 8, c = i & 255; w1T[c * 64 + o] = w1[i]; }    // w1 [64][256] -> [c][o]
  if (i < 36864) {
    // deform B-frags: [kt=18][n=4][lane=64][j=8]; elem = Wd[K=kt*32+(lane>>4)*8+j][o=n*16+(lane&15)]
    int j = i & 7;
    int lane = (i >> 3) & 63;
    int n = (i >> 9) & 3;
    int kt = i >> 11;
    int kk = kt * 32 + ((lane >> 4) << 3) + j;
    int tap = kk >> 6, c = kk & 63;
    int o = (n << 4) + (lane & 15);
    wBf[i] = f2bf(wdef[(size_t)o * 576 + c * 9 + tap]);
  }
  if (i < 18432) {
    // offs-conv B-frags: [kt=18][n=2][lane=64][j=8]; zero-pad o>=18
    int j = i & 7;
    int lane = (i >> 3) & 63;
    int n = (i >> 9) & 1;
    int kt = i >> 10;
    int kk = kt * 32 + ((lane >> 4) << 3) + j;
    int tap = kk >> 6, c = kk & 63;
    int o = (n << 4) + (lane & 15);
    wofBf[i] = (o < 18) ? f2bf(woff[((size_t)(o * 64 + c)) * 9 + tap]) : (unsigned short)0;
  }
  if (i < 32768) {
    // conv2 B-frags: [kt=2][n=16][lane=64][j=8]; elem = W3[k=kt*32+(lane>>4)*8+j][o=n*16+(lane&15)]
    // w3 [256 o][64 c]
    int j = i & 7;
    int lane = (i >> 3) & 63;
    int n = (i >> 9) & 15;
    int kt = i >> 13;
    int c = kt * 32 + ((lane >> 4) << 3) + j;
    int o = (n << 4) + (lane & 15);
    w3Bf[i] = f2bf(w3[(size_t)o * 64 + c]);
  }
}

// ---- K1: conv1x1 256->64 + fused GN1 partial stats ----
__global__ __launch_bounds__(512) void k_conv1(const float* __restrict__ x, const float* __restrict__ w1T,
                                               float* __restrict__ y, float* __restrict__ ps) {
  int tid = threadIdx.x;
  int lane = tid & 63;
  int o0 = __builtin_amdgcn_readfirstlane(tid >> 6) * 8;
  int b = blockIdx.x >> 6;
  int chunk = blockIdx.x & 63;
  int hw = (chunk << 8) + (lane << 2);
  const float* xb = x + (size_t)b * 256 * HW + hw;
  float acc[8][4];
#pragma unroll
  for (int i = 0; i < 8; i++)
#pragma unroll
    for (int j = 0; j < 4; j++) acc[i][j] = 0.f;
#pragma unroll 4
  for (int c = 0; c < 256; c++) {
    float4 xv = *(const float4*)(xb + (size_t)c * HW);
    const float* wp = w1T + c * 64 + o0;  // wave-uniform -> s_load
#pragma unroll
    for (int i = 0; i < 8; i++) {
      float w = wp[i];
      acc[i][0] += xv.x * w; acc[i][1] += xv.y * w;
      acc[i][2] += xv.z * w; acc[i][3] += xv.w * w;
    }
  }
  float* yb = y + (size_t)b * 64 * HW + hw;
#pragma unroll
  for (int i = 0; i < 8; i++)
    *(float4*)(yb + (size_t)(o0 + i) * HW) = make_float4(acc[i][0], acc[i][1], acc[i][2], acc[i][3]);
  float gs[4], gss[4];
#pragma unroll
  for (int k = 0; k < 4; k++) {
    float a = 0.f, q = 0.f;
#pragma unroll
    for (int t = 0; t < 2; t++)
#pragma unroll
      for (int j = 0; j < 4; j++) { float v = acc[2 * k + t][j]; a += v; q += v * v; }
    gs[k] = a; gss[k] = q;
  }
#pragma unroll
  for (int k = 0; k < 4; k++) {
#pragma unroll
    for (int off = 32; off; off >>= 1) { gs[k] += __shfl_down(gs[k], off); gss[k] += __shfl_down(gss[k], off); }
  }
  if (lane == 0) {
    int g0 = o0 >> 1;
#pragma unroll
    for (int k = 0; k < 4; k++) {
      int bg = b * 32 + g0 + k;
      ps[(bg * 64 + chunk) * 2] = gs[k];
      ps[(bg * 64 + chunk) * 2 + 1] = gss[k];
    }
  }
}

// ---- K2: finalize GN stats (S chunks per bg) ----
__global__ __launch_bounds__(128) void k_gnfin(const float* __restrict__ ps, float* __restrict__ mrs,
                                               int S, float n) {
  int bg = threadIdx.x;
  float s = 0.f, ss = 0.f;
  for (int sl = 0; sl < S; sl++) { s += ps[(bg * S + sl) * 2]; ss += ps[(bg * S + sl) * 2 + 1]; }
  float mu = s / n;
  float var = ss / n - mu * mu;
  mrs[bg] = mu;
  mrs[128 + bg] = rsqrtf(var + 1e-5f);
}

// ---- K3: apply GN1 + ReLU; read NCHW xd, write NHWC xdT via LDS transpose ----
__global__ __launch_bounds__(256) void k_gnapply_t(const float* __restrict__ xd, float* __restrict__ xdT,
                                                   const float* __restrict__ mrs,
                                                   const float* __restrict__ g1, const float* __restrict__ b1) {
  __shared__ float tile[64 * 65];
  int tid = threadIdx.x;
  int b = blockIdx.x >> 8;
  int p0 = (blockIdx.x & 255) << 6;
  int lane = tid & 63;
  int w = tid >> 6;
  const size_t bbase = (size_t)b * 64 * HW;
#pragma unroll
  for (int j = 0; j < 16; j++) {
    int c = w * 16 + j;
    int g = c >> 1;
    float mu = mrs[b * 32 + g], rs = mrs[128 + b * 32 + g];
    float ga = g1[c] * rs, be = b1[c] - mu * ga;
    float v = xd[bbase + (size_t)c * HW + p0 + lane];
    v = fmaxf(v * ga + be, 0.f);
    tile[lane * 65 + c] = v;
  }
  __syncthreads();
#pragma unroll
  for (int j = 0; j < 16; j++) {
    int px = w * 16 + j;
    xdT[((size_t)b * HW + p0 + px) * 64 + lane] = tile[px * 65 + lane];  // NHWC
  }
}

// ---- K4: offsets conv3x3 64->18 via bf16 MFMA (fixed-tap im2col GEMM) ----
__global__ __launch_bounds__(576, 2) void k_off_mfma(const float* __restrict__ xdT,
                                                     const unsigned short* __restrict__ wofBf,
                                                     float* __restrict__ offs) {
  __shared__ unsigned short A[72 * 65 * 8];  // 74,880 B
  int tid = threadIdx.x;
  int bb = blockIdx.x >> 8;
  int px0 = (blockIdx.x & 255) << 6;
  const char* xbt = (const char*)(xdT + (size_t)bb * 64 * HW);
  int wave = tid >> 6;  // tap 0..8
  int lane = tid & 63;
  {
    int q = lane >> 4;
    int ch = lane & 15;
    int co = ch << 4;
    int kcb = wave * 8 + (ch >> 1);
    int wbase = kcb * (65 * 16) + ((ch & 1) << 3);
    int ky = wave / 3 - 1, kx = wave % 3 - 1;
#pragma unroll 2
    for (int g = 0; g < 16; ++g) {
      int src = 4 * g + q;
      int px = px0 + src;
      int sy = (px >> 7) + ky;
      int sx = (px & 127) + kx;
      bool valid = ((unsigned)sy < 128u) && ((unsigned)sx < 128u);
      float4 v = make_float4(0.f, 0.f, 0.f, 0.f);
      if (valid) v = *(const float4*)(xbt + (((sy << 7) + sx) << 8) + co);
      unsigned int r0, r1;
      asm("v_cvt_pk_bf16_f32 %0, %1, %2" : "=v"(r0) : "v"(v.x), "v"(v.y));
      asm("v_cvt_pk_bf16_f32 %0, %1, %2" : "=v"(r1) : "v"(v.z), "v"(v.w));
      *(uint2*)((char*)A + wbase + src * 16) = make_uint2(r0, r1);
    }
  }
  __syncthreads();
  if (wave >= 8) return;
  int n = wave & 1;
  int mh = wave >> 1;
  int r0r = mh * 16 + (lane & 15);
  int kq = lane >> 4;
  const bf16x8* wp = (const bf16x8*)wofBf;
  f32x4 acc = {0.f, 0.f, 0.f, 0.f};
#pragma unroll 3
  for (int kt = 0; kt < 18; kt++) {
    bf16x8 bk = wp[(kt * 2 + n) * 64 + lane];
    int kc = kt * 4 + kq;
    bf16x8 a0 = *(const bf16x8*)((const char*)A + (kc * 65 + r0r) * 16);
    acc = __builtin_amdgcn_mfma_f32_16x16x32_bf16(a0, bk, acc, 0, 0, 0);
  }
  int o = n * 16 + (lane & 15);
  if (o < 18) {
    int prow = mh * 16 + ((lane >> 4) << 2);
    float* op = offs + (size_t)bb * 18 * HW + (size_t)o * HW + px0 + prow;
#pragma unroll
    for (int r = 0; r < 4; r++) op[r] = acc[r];
  }
}

// ---- K5: fused deform conv + residual + conv1x1 64->256 + GN2 partials, all MFMA.
// Phase A: bilinear gather -> A1[72 kc][65 row][16B] bf16 (as round 8).
// Phase B: GEMM1 (waves 0-7): D1[64px][64c] = A1 @ Wd; + residual from xdT.
// Phase C: D1 -> bf16 -> A2[8 kc][65 row][16B] (overwrites A1 head after barrier).
// Phase D: GEMM2: t3[64px][256o] = A2 @ W3; GN2 partials from regs; bf16 stores.
__global__ __launch_bounds__(576, 5) void k_dcf(const float* __restrict__ xdT,
                                                const float* __restrict__ offs,
                                                const unsigned short* __restrict__ wBf,
                                                const unsigned short* __restrict__ w3Bf,
                                                unsigned short* __restrict__ t3,
                                                float* __restrict__ ps2) {
  __shared__ unsigned short A[72 * 65 * 8];  // 74,880 B
  int tid = threadIdx.x;
  int bb = blockIdx.x >> 8;
  int tileid = blockIdx.x & 255;
  int px0 = tileid << 6;
  const float* xtf = xdT + (size_t)bb * 64 * HW;
  const char* xbt = (const char*)xtf;
  int wave = tid >> 6;
  int lane = tid & 63;

  // geometry for pair (pxl=lane, tap=wave)
  float w00, w01, w10, w11;
  int a00, a01, a10, a11;
  {
    int px = px0 + lane;
    int y = px >> 7, xc = px & 127;
    const float* ob = offs + (size_t)bb * 18 * HW + px;
    float dy = ob[(size_t)(2 * wave) * HW];
    float dx = ob[(size_t)(2 * wave + 1) * HW];
    float py = (float)(y + wave / 3 - 1) + dy;
    float pxx = (float)(xc + wave % 3 - 1) + dx;
    float y0f = floorf(py), x0f = floorf(pxx);
    float ay = py - y0f, ax = pxx - x0f;
    int y0 = (int)y0f, x0 = (int)x0f;
    int y1i = y0 + 1, x1i = x0 + 1;
    float by0 = 1.f - ay, bx0 = 1.f - ax;
    bool vy0 = (unsigned)y0 < 128u, vy1 = (unsigned)y1i < 128u;
    bool vx0 = (unsigned)x0 < 128u, vx1 = (unsigned)x1i < 128u;
    w00 = (vy0 && vx0) ? by0 * bx0 : 0.f;
    w01 = (vy0 && vx1) ? by0 * ax : 0.f;
    w10 = (vy1 && vx0) ? ay * bx0 : 0.f;
    w11 = (vy1 && vx1) ? ay * ax : 0.f;
    int iy0 = min(max(y0, 0), 127), iy1 = min(max(y1i, 0), 127);
    int ix0 = min(max(x0, 0), 127), ix1 = min(max(x1i, 0), 127);
    a00 = (iy0 * WIDTH + ix0) << 8;
    a01 = (iy0 * WIDTH + ix1) << 8;
    a10 = (iy1 * WIDTH + ix0) << 8;
    a11 = (iy1 * WIDTH + ix1) << 8;
  }

  // Phase A: gather (4 pairs/iter; lane = (q, ch-chunk))
  {
    int q = lane >> 4;
    int ch = lane & 15;
    int co = ch << 4;
    int kcb = wave * 8 + (ch >> 1);
    int wbase = kcb * (65 * 16) + ((ch & 1) << 3);
#pragma unroll 2
    for (int g = 0; g < 16; ++g) {
      int src = 4 * g + q;
      float j0 = __shfl(w00, src), j1 = __shfl(w01, src);
      float j2 = __shfl(w10, src), j3 = __shfl(w11, src);
      int b0 = __shfl(a00, src), b1 = __shfl(a01, src);
      int b2 = __shfl(a10, src), b3 = __shfl(a11, src);
      float4 v0 = *(const float4*)(xbt + b0 + co);
      float4 v1 = *(const float4*)(xbt + b1 + co);
      float4 v2 = *(const float4*)(xbt + b2 + co);
      float4 v3 = *(const float4*)(xbt + b3 + co);
      float sx = j0 * v0.x + j1 * v1.x + j2 * v2.x + j3 * v3.x;
      float sy = j0 * v0.y + j1 * v1.y + j2 * v2.y + j3 * v3.y;
      float sz = j0 * v0.z + j1 * v1.z + j2 * v2.z + j3 * v3.z;
      float sw = j0 * v0.w + j1 * v1.w + j2 * v2.w + j3 * v3.w;
      unsigned int r0, r1;
      asm("v_cvt_pk_bf16_f32 %0, %1, %2" : "=v"(r0) : "v"(sx), "v"(sy));
      asm("v_cvt_pk_bf16_f32 %0, %1, %2" : "=v"(r1) : "v"(sz), "v"(sw));
      *(uint2*)((char*)A + wbase + src * 16) = make_uint2(r0, r1);
    }
  }
  __syncthreads();

  // Phase B: GEMM1 + residual (waves 0..7)
  int n1 = wave & 3;
  int mh = wave >> 2;
  f32x4 acc0 = {0.f, 0.f, 0.f, 0.f};
  f32x4 acc1 = {0.f, 0.f, 0.f, 0.f};
  if (wave < 8) {
    int r0r = mh * 32 + (lane & 15);
    int kq = lane >> 4;
    const bf16x8* wp = (const bf16x8*)wBf;
#pragma unroll 3
    for (int kt = 0; kt < 18; kt++) {
      bf16x8 bk = wp[(kt * 4 + n1) * 64 + lane];
      int kc = kt * 4 + kq;
      bf16x8 a0 = *(const bf16x8*)((const char*)A + (kc * 65 + r0r) * 16);
      bf16x8 a1 = *(const bf16x8*)((const char*)A + (kc * 65 + r0r + 16) * 16);
      acc0 = __builtin_amdgcn_mfma_f32_16x16x32_bf16(a0, bk, acc0, 0, 0, 0);
      acc1 = __builtin_amdgcn_mfma_f32_16x16x32_bf16(a1, bk, acc1, 0, 0, 0);
    }
    int c = n1 * 16 + (lane & 15);
    int pb = px0 + mh * 32 + ((lane >> 4) << 2);
#pragma unroll
    for (int r = 0; r < 4; r++) {
      acc0[r] += xtf[(size_t)(pb + r) * 64 + c];
      acc1[r] += xtf[(size_t)(pb + 16 + r) * 64 + c];
    }
  }
  __syncthreads();  // all A1 reads complete

  // Phase C: write A2 (bf16, chunk-major [kc=8][row pad65][16B]) into A's head
  if (wave < 8) {
    int c = n1 * 16 + (lane & 15);
    char* base = (char*)A + (c >> 3) * 1040 + (c & 7) * 2;
    int pxr = mh * 32 + ((lane >> 4) << 2);
#pragma unroll
    for (int r = 0; r < 4; r++) {
      *(unsigned short*)(base + (size_t)(pxr + r) * 16) = f2bf(acc0[r]);
      *(unsigned short*)(base + (size_t)(pxr + 16 + r) * 16) = f2bf(acc1[r]);
    }
  }
  __syncthreads();
  if (wave >= 8) return;

  // Phase D: GEMM2 (M=64, N=256, K=64): wave -> px-half (wave>>2), n-quad (wave&3)
  f32x4 cA[4], cB[4];
#pragma unroll
  for (int ni = 0; ni < 4; ni++) {
    cA[ni] = (f32x4){0.f, 0.f, 0.f, 0.f};
    cB[ni] = (f32x4){0.f, 0.f, 0.f, 0.f};
  }
  {
    int kq = lane >> 4;
    int mt0 = (wave >> 2) * 2;
    const bf16x8* wp2 = (const bf16x8*)w3Bf;
#pragma unroll
    for (int kt = 0; kt < 2; kt++) {
      int kc = kt * 4 + kq;
      bf16x8 aA = *(const bf16x8*)((const char*)A + (size_t)(kc * 65 + mt0 * 16 + (lane & 15)) * 16);
      bf16x8 aB = *(const bf16x8*)((const char*)A + (size_t)(kc * 65 + (mt0 + 1) * 16 + (lane & 15)) * 16);
#pragma unroll
      for (int ni = 0; ni < 4; ni++) {
        int ng = n1 * 4 + ni;
        bf16x8 bk = wp2[(kt * 16 + ng) * 64 + lane];
        cA[ni] = __builtin_amdgcn_mfma_f32_16x16x32_bf16(aA, bk, cA[ni], 0, 0, 0);
        cB[ni] = __builtin_amdgcn_mfma_f32_16x16x32_bf16(aB, bk, cB[ni], 0, 0, 0);
      }
    }
  }
  // GN2 partials from regs: group g = o>>3; wave covers px-half (wave>>2)
#pragma unroll
  for (int ni = 0; ni < 4; ni++) {
    float s = 0.f, q = 0.f;
#pragma unroll
    for (int r = 0; r < 4; r++) {
      float v0 = cA[ni][r], v1 = cB[ni][r];
      s += v0 + v1; q += v0 * v0 + v1 * v1;
    }
    s += __shfl_down(s, 32); q += __shfl_down(q, 32);
    s += __shfl_down(s, 16); q += __shfl_down(q, 16);
    s += __shfl_down(s, 4);  q += __shfl_down(q, 4);
    s += __shfl_down(s, 2);  q += __shfl_down(q, 2);
    s += __shfl_down(s, 1);  q += __shfl_down(q, 1);
    if (lane == 0 || lane == 8) {
      int g = (n1 * 4 + ni) * 2 + (lane >> 3);
      int slot = ((bb * 32 + g) * 256 + tileid) * 2 + (wave >> 2);
      ps2[slot * 2] = s;
      ps2[slot * 2 + 1] = q;
    }
  }
  // bf16 t3 stores (NCHW): per o, 4 quads x 8B = full 64B lines
  unsigned short* tb = t3 + (size_t)bb * 256 * HW + px0;
  int mtq = (wave >> 2) * 32 + ((lane >> 4) << 2);
#pragma unroll
  for (int ni = 0; ni < 4; ni++) {
    int o = (n1 * 4 + ni) * 16 + (lane & 15);
    unsigned short* p0 = tb + (size_t)o * HW + mtq;
    unsigned int u0, u1, u2, u3;
    asm("v_cvt_pk_bf16_f32 %0, %1, %2" : "=v"(u0) : "v"(cA[ni][0]), "v"(cA[ni][1]));
    asm("v_cvt_pk_bf16_f32 %0, %1, %2" : "=v"(u1) : "v"(cA[ni][2]), "v"(cA[ni][3]));
    asm("v_cvt_pk_bf16_f32 %0, %1, %2" : "=v"(u2) : "v"(cB[ni][0]), "v"(cB[ni][1]));
    asm("v_cvt_pk_bf16_f32 %0, %1, %2" : "=v"(u3) : "v"(cB[ni][2]), "v"(cB[ni][3]));
    *(uint2*)p0 = make_uint2(u0, u1);
    *(uint2*)(p0 + 16) = make_uint2(u2, u3);
  }
}

// ---- K7: finalize GN2 stats (512 slots per bg) ----
__global__ __launch_bounds__(128) void k_gnfin2(const float* __restrict__ ps2, float* __restrict__ mrs) {
  int bg = threadIdx.x;
  float s = 0.f, ss = 0.f;
  for (int i = 0; i < 512; i++) { s += ps2[(bg * 512 + i) * 2]; ss += ps2[(bg * 512 + i) * 2 + 1]; }
  const float n = 131072.f;
  float mu = s / n;
  float var = ss / n - mu * mu;
  mrs[bg] = mu;
  mrs[128 + bg] = rsqrtf(var + 1e-5f);
}

// ---- K8: out = relu(gn2(t3_bf16)) + x ----
__global__ __launch_bounds__(256) void k_final(const unsigned short* __restrict__ t3, const float* __restrict__ x,
                                               const float* __restrict__ mrs, const float* __restrict__ g3,
                                               const float* __restrict__ b3, float* __restrict__ out) {
  int i4 = blockIdx.x * 256 + threadIdx.x;
  int b = i4 >> 20;
  int c = (i4 >> 12) & 255;
  int g = c >> 3;
  float mu = mrs[b * 32 + g], rs = mrs[128 + b * 32 + g];
  float ga = g3[c] * rs, be = b3[c] - mu * ga;
  uint2 tv = ((const uint2*)t3)[i4];
  float t0 = __uint_as_float(tv.x << 16);
  float t1 = __uint_as_float(tv.x & 0xffff0000u);
  float t2 = __uint_as_float(tv.y << 16);
  float t3v = __uint_as_float(tv.y & 0xffff0000u);
  float4 xv = ((const float4*)x)[i4];
  float4 r;
  r.x = fmaxf(t0 * ga + be, 0.f) + xv.x;
  r.y = fmaxf(t1 * ga + be, 0.f) + xv.y;
  r.z = fmaxf(t2 * ga + be, 0.f) + xv.z;
  r.w = fmaxf(t3v * ga + be, 0.f) + xv.w;
  ((float4*)out)[i4] = r;
}

extern "C" void kernel_launch(void* const* d_in, const int* in_sizes, int n_in,
                              void* d_out, int out_size, void* d_ws, size_t ws_size,
                              hipStream_t stream) {
  const float* x    = (const float*)d_in[0];
  const float* w1   = (const float*)d_in[1];
  const float* g1   = (const float*)d_in[2];
  const float* b1   = (const float*)d_in[3];
  const float* woff = (const float*)d_in[4];
  const float* wdef = (const float*)d_in[5];
  const float* w3   = (const float*)d_in[6];
  const float* g3   = (const float*)d_in[7];
  const float* b3   = (const float*)d_in[8];
  float* ws = (float*)d_ws;

  float* xd   = ws;                       // 4,194,304
  float* offs = xd + 4194304;             // 1,179,648
  float* xdT  = offs + 1179648;           // 4,194,304 (NHWC)
  unsigned short* t3 = (unsigned short*)(xdT + 4194304);  // 16,777,216 ush = 8,388,608 fl
  float* after = xdT + 4194304 + 8388608;
  float* mrs1 = after;                    // 256
  float* mrs2 = mrs1 + 256;               // 256
  float* w1T  = mrs2 + 256;               // 16,384
  unsigned short* wBf   = (unsigned short*)(w1T + 16384);   // 36,864 ush = 18,432 fl
  unsigned short* wofBf = (unsigned short*)(w1T + 16384 + 18432);  // 18,432 ush = 9,216 fl
  unsigned short* w3Bf  = (unsigned short*)(w1T + 16384 + 18432 + 9216);  // 32,768 ush = 16,384 fl
  float* ps   = w1T + 16384 + 18432 + 9216 + 16384;  // 16,384
  float* ps2  = ps + 16384;               // 131,072
  float* out  = (float*)d_out;

  hipLaunchKernelGGL(k_prep, dim3(144), dim3(256), 0, stream, w1, w3, wdef, woff, w1T, wBf, wofBf, w3Bf);
  hipLaunchKernelGGL(k_conv1, dim3(256), dim3(512), 0, stream, x, w1T, xd, ps);
  hipLaunchKernelGGL(k_gnfin, dim3(1), dim3(128), 0, stream, ps, mrs1, 64, (float)(2 * HW));
  hipLaunchKernelGGL(k_gnapply_t, dim3(1024), dim3(256), 0, stream, xd, xdT, mrs1, g1, b1);
  hipLaunchKernelGGL(k_off_mfma, dim3(1024), dim3(576), 0, stream, xdT, wofBf, offs);
  hipLaunchKernelGGL(k_dcf, dim3(1024), dim3(576), 0, stream, xdT, offs, wBf, w3Bf, t3, ps2);
  hipLaunchKernelGGL(k_gnfin2, dim3(1), dim3(128), 0, stream, ps2, mrs2);
  hipLaunchKernelGGL(k_final, dim3(16384), dim3(256), 0, stream, t3, x, mrs2, g3, b3, out);
}